// Round 17
// baseline (800.755 us; speedup 1.0000x reference)
//
#include <hip/hip_runtime.h>
#include <hip/hip_fp16.h>

#define B 256
#define T 128
#define D 76
#define H 128
#define G 512   // 4H
#define H2 256  // 2H

typedef unsigned int uint32;
typedef unsigned short ushort16;
typedef _Float16 h2_t __attribute__((ext_vector_type(2)));

__device__ __forceinline__ float sigm(float x){ return 1.0f/(1.0f+__expf(-x)); }
__device__ __forceinline__ float fast_rcp(float x){ float r; asm volatile("v_rcp_f32 %0, %1" : "=v"(r) : "v"(x)); return r; }
__device__ __forceinline__ float fast_tanh(float x){ return 1.0f - 2.0f*fast_rcp(1.0f + __expf(2.0f*x)); }
__device__ __forceinline__ float bflo(uint32 u){ return __uint_as_float(u<<16); }
__device__ __forceinline__ float bfhi(uint32 u){ return __uint_as_float(u & 0xffff0000u); }
__device__ __forceinline__ ushort16 f2bf(float f){ uint32 u=__float_as_uint(f); return (ushort16)((u + 0x7fffu + ((u>>16)&1u))>>16); }
__device__ __forceinline__ uint32 pk_f16(float a, float b){
  return (uint32)__half_as_ushort(__float2half(a)) | ((uint32)__half_as_ushort(__float2half(b))<<16);
}
__device__ __forceinline__ float dot2(uint32 w, uint32 h, float acc){
  return __builtin_amdgcn_fdot2(__builtin_bit_cast(h2_t, w), __builtin_bit_cast(h2_t, h), acc, false);
}

// ---------- weight transposes (2 segs: Wzmu, Wzlv) ----------
struct PrepArgs {
  const float* src[2];
  float* dst[2];
  int R[2]; int C[2];
};
__global__ __launch_bounds__(256) void prep_k(PrepArgs a){
  int seg = blockIdx.x >> 5;
  const float* s=a.src[seg]; float* d=a.dst[seg];
  int R=a.R[seg], C=a.C[seg], tot=R*C;
  for (int i=(blockIdx.x&31)*256+threadIdx.x; i<tot; i+=32*256){
    int r=i/C, c=i-r*C;
    d[(size_t)c*R + r] = s[i];
  }
}

// ---------- pack [N][K] f32 row-major -> [K/2][N] f16-pair u32 (9 segs) ----------
struct Pack2Args { const float* src[9]; uint32* dst[9]; int N[9]; int K[9]; };
__global__ __launch_bounds__(256) void pack2_k(Pack2Args a){
  int seg = blockIdx.x >> 5;
  const float* s=a.src[seg]; uint32* d=a.dst[seg];
  int N=a.N[seg], K=a.K[seg], tot=N*(K>>1);
  for (int i=(blockIdx.x&31)*256+threadIdx.x; i<tot; i+=32*256){
    int k2=i/N, j=i-k2*N;
    float2 w = *(const float2*)(s + (size_t)j*K + 2*k2);
    d[(size_t)k2*N + j] = pk_f16(w.x, w.y);
  }
}

// ---------- pack Whh (enc+dec) f16 k-pairs, columns PERMUTED for in-wave gate exchange ----------
__global__ __launch_bounds__(256) void pack_whh_k(
  const float* __restrict__ eWhh, const float* __restrict__ dWhh,
  uint32* __restrict__ wpkE, uint32* __restrict__ wpkD)
{
  int idx = blockIdx.x*256 + threadIdx.x;      // 131072 total
  int phase = idx >> 16;
  int rem = idx & 65535;
  int d = rem >> 15;
  int k2 = (rem >> 9) & 63;
  int jc = rem & 511;
  int gate = (jc>>4)&3;
  int cell = (jc&15) + 16*(jc>>6);
  int jsrc = gate*128 + cell;
  const float* Wsrc = phase ? dWhh : eWhh;
  float2 wa = *(const float2*)(Wsrc + ((size_t)(d*512 + jsrc))*128 + 2*k2);
  (phase ? wpkD : wpkE)[rem] = pk_f16(wa.x, wa.y);
}

// ---------- xg = x @ Wih^T + b via f16 dot2, flat f16 [d][b][t][512]. shift=1 for decoder ----------
__global__ __launch_bounds__(256) void xg_k(
  const float* __restrict__ x, const uint32* __restrict__ wx, const float* __restrict__ bias,
  __half* __restrict__ xgh, int shift)
{
  int d = blockIdx.x >> 11;
  int blk = blockIdx.x & 2047;
  int b = blk >> 3, t0 = (blk & 7) * 16;
  int tid = threadIdx.x;
  __shared__ __align__(16) uint32 xs[16][40];
  for (int i=tid;i<16*38;i+=256){
    int r=i/38, k2=i-r*38, ts=t0+r-shift;
    float2 xv = (ts>=0) ? *(const float2*)(x + ((size_t)b*T+ts)*D + 2*k2) : make_float2(0.f,0.f);
    xs[r][k2] = pk_f16(xv.x, xv.y);
  }
  __syncthreads();
  const uint32* W = wx + (size_t)d*38*512;
  float a0[16], a1[16];
  #pragma unroll
  for(int r=0;r<16;r++){a0[r]=0.f;a1[r]=0.f;}
  #pragma unroll
  for (int k8=0;k8<9;k8++){
    int k2=4*k8;
    uint32 w00=W[(size_t)(k2+0)*512+tid], w01=W[(size_t)(k2+0)*512+tid+256];
    uint32 w10=W[(size_t)(k2+1)*512+tid], w11=W[(size_t)(k2+1)*512+tid+256];
    uint32 w20=W[(size_t)(k2+2)*512+tid], w21=W[(size_t)(k2+2)*512+tid+256];
    uint32 w30=W[(size_t)(k2+3)*512+tid], w31=W[(size_t)(k2+3)*512+tid+256];
    #pragma unroll
    for(int r=0;r<16;r++){
      uint4 u = *(const uint4*)&xs[r][k2];
      a0[r]=dot2(u.x,w00,a0[r]); a0[r]=dot2(u.y,w10,a0[r]);
      a0[r]=dot2(u.z,w20,a0[r]); a0[r]=dot2(u.w,w30,a0[r]);
      a1[r]=dot2(u.x,w01,a1[r]); a1[r]=dot2(u.y,w11,a1[r]);
      a1[r]=dot2(u.z,w21,a1[r]); a1[r]=dot2(u.w,w31,a1[r]);
    }
  }
  {
    uint32 w00=W[(size_t)36*512+tid], w01=W[(size_t)36*512+tid+256];
    uint32 w10=W[(size_t)37*512+tid], w11=W[(size_t)37*512+tid+256];
    #pragma unroll
    for(int r=0;r<16;r++){
      uint2 u = *(const uint2*)&xs[r][36];
      a0[r]=dot2(u.x,w00,a0[r]); a0[r]=dot2(u.y,w10,a0[r]);
      a1[r]=dot2(u.x,w01,a1[r]); a1[r]=dot2(u.y,w11,a1[r]);
    }
  }
  float bb0=bias[d*G+tid], bb1=bias[d*G+tid+256];
  #pragma unroll
  for(int r=0;r<16;r++){
    size_t row = (size_t)(d*B + b)*T + (t0+r);
    xgh[row*512 + tid]       = __float2half(a0[r]+bb0);
    xgh[row*512 + tid + 256] = __float2half(a1[r]+bb1);
  }
}

// ---------- recurrence: in-wave gate exchange; 1 barrier/iter; hsd double-buffered ----------
template<int ENC>
__global__ __launch_bounds__(512,2) void rec_k(
  const __half* __restrict__ xgh, const uint32* __restrict__ wpk,
  const __half* __restrict__ h16r, __half* __restrict__ on16,
  float* __restrict__ h_fin, uint32* __restrict__ h16w)
{
  int d = blockIdx.x >> 8;
  int b = blockIdx.x & 255;
  int tid = threadIdx.x;
  int lane = tid & 63;
  int gate = lane >> 4;
  int cell = (lane & 15) + 16*(tid >> 6);
  int jmap = gate*128 + cell;
  __shared__ __align__(16) __half hsd[2][H];
  uint32 wreg[64];
  const uint32* wp = wpk + (size_t)d*64*512;
  #pragma unroll
  for (int k2=0;k2<64;k2++) wreg[k2] = wp[k2*512 + tid];
  if (tid < H){
    if (ENC) hsd[0][tid] = __float2half(0.f);
    else     hsd[0][tid] = h16r[((size_t)d*B + b)*H + tid];
  }
  float creg = 0.f, hlast = 0.f;
  const __half* xrow = xgh + (size_t)(d*B + b)*T*512;
  int te0 = ENC ? (d ? (T-1) : 0) : 0;
  __half xr_next = xrow[(size_t)te0*512 + jmap];
  __syncthreads();
  int p = 0;
  for (int t=0;t<T;t++){
    int te = ENC ? (d ? (T-1-t) : t) : t;
    __half xr = xr_next;
    if (t+1 < T){
      int tn = ENC ? (d ? (T-2-t) : (t+1)) : (t+1);
      xr_next = xrow[(size_t)tn*512 + jmap];
    }
    const uint4* h128 = (const uint4*)hsd[p];
    float acc0 = 0.f, acc1 = 0.f;
    #pragma unroll
    for (int k8=0;k8<16;k8++){
      uint4 hv4 = h128[k8];
      acc0 = dot2(wreg[4*k8+0], hv4.x, acc0);
      acc1 = dot2(wreg[4*k8+1], hv4.y, acc1);
      acc0 = dot2(wreg[4*k8+2], hv4.z, acc0);
      acc1 = dot2(wreg[4*k8+3], hv4.w, acc1);
    }
    float gpre = acc0 + acc1 + __half2float(xr);
    float kmul = (gate==2) ? 2.f : 1.f;
    float s = sigm(kmul*gpre);
    float act = (gate==2) ? fmaf(2.f, s, -1.f) : s;
    int src = lane & 15;
    float f_ = __shfl(act, src+16, 64);
    float g_ = __shfl(act, src+32, 64);
    float o_ = __shfl(act, src+48, 64);
    if (gate==0){
      creg = f_*creg + act*g_;
      float hv = o_*fast_tanh(creg);
      hlast = hv;
      hsd[p^1][cell] = __float2half(hv);
      if (ENC){
        on16[((size_t)b*T + te)*H2 + d*H + cell] = __float2half(hv);
      } else {
        float nb = __shfl_xor(hv, 1);
        if ((cell&1)==0)
          h16w[(((size_t)(t+1)*2 + d)*B + b)*64 + (cell>>1)] = pk_f16(hv, nb);
      }
    }
    __syncthreads();
    p ^= 1;
  }
  if (ENC && gate==0) h_fin[(size_t)d*B*H + (size_t)b*H + cell] = hlast;
}

// ---------- z = mu + eps*exp(0.5 lv) -> h16[0] (f16 pairs) ----------
__global__ __launch_bounds__(128) void z_k(
  const float* __restrict__ h_fin, const float* __restrict__ WzmuT, const float* __restrict__ bzmu,
  const float* __restrict__ WzlvT, const float* __restrict__ bzlv, const float* __restrict__ eps_z,
  uint32* __restrict__ h16w)
{
  __shared__ float hr[H];
  int d = blockIdx.x >> 8; int b = blockIdx.x & 255;
  int j = threadIdx.x;
  hr[j] = h_fin[(size_t)d*B*H + (size_t)b*H + j];
  __syncthreads();
  float mu=bzmu[j], lv=bzlv[j];
  #pragma unroll 4
  for(int k=0;k<H;k++){ float hv=hr[k]; mu+=hv*WzmuT[k*H+j]; lv+=hv*WzlvT[k*H+j]; }
  float z = mu + eps_z[(size_t)d*B*H + (size_t)b*H + j]*__expf(0.5f*lv);
  float nb = __shfl_xor(z, 1);
  if ((j&1)==0)
    h16w[(((size_t)0*2 + d)*B + b)*64 + (j>>1)] = pk_f16(z, nb);
}

// ---------- fused on_s (f16 dot2 GEMMs, b128 LDS), 32 rows/block: onsT + eb ----------
__global__ __launch_bounds__(256) void onsw2v_k(
  const uint32* __restrict__ on32, const uint32* __restrict__ wpmu, const float* __restrict__ bomu,
  const uint32* __restrict__ wplv, const float* __restrict__ bolv, const float* __restrict__ eps_on,
  const uint32* __restrict__ wp2, const float* __restrict__ b2,
  uint32* __restrict__ onsT, float* __restrict__ ebg)
{
  __shared__ __align__(16) uint32 tl[32][128];     // on (f16 pairs along k), 16 KB
  __shared__ __align__(16) uint32 t2p[32][128];    // on_s (f16 pairs along j), 16 KB
  size_t row0=(size_t)blockIdx.x*32;
  int b = (int)(row0 >> 7), t0 = (int)(row0 & 127);   // t0 in {0,32,64,96}
  int tid=threadIdx.x;
  for(int i=tid;i<32*128;i+=256) ((uint32*)tl)[i] = on32[row0*128 + i];
  __syncthreads();
  float am[32], al[32];
  #pragma unroll
  for(int r=0;r<32;r++){am[r]=0.f;al[r]=0.f;}
  for(int k8=0;k8<32;k8++){
    int k2=4*k8;
    uint32 wm0=wpmu[(size_t)(k2+0)*H2+tid], wm1=wpmu[(size_t)(k2+1)*H2+tid];
    uint32 wm2=wpmu[(size_t)(k2+2)*H2+tid], wm3=wpmu[(size_t)(k2+3)*H2+tid];
    uint32 wl0=wplv[(size_t)(k2+0)*H2+tid], wl1=wplv[(size_t)(k2+1)*H2+tid];
    uint32 wl2=wplv[(size_t)(k2+2)*H2+tid], wl3=wplv[(size_t)(k2+3)*H2+tid];
    #pragma unroll
    for(int r=0;r<32;r++){
      uint4 u = *(const uint4*)&tl[r][k2];
      am[r]=dot2(u.x,wm0,am[r]); am[r]=dot2(u.y,wm1,am[r]);
      am[r]=dot2(u.z,wm2,am[r]); am[r]=dot2(u.w,wm3,am[r]);
      al[r]=dot2(u.x,wl0,al[r]); al[r]=dot2(u.y,wl1,al[r]);
      al[r]=dot2(u.z,wl2,al[r]); al[r]=dot2(u.w,wl3,al[r]);
    }
  }
  float bm=bomu[tid], bl=bolv[tid];
  #pragma unroll
  for(int r=0;r<32;r++){
    size_t row=row0+r;
    float v = am[r]+bm + eps_on[row*H2+tid]*__expf(0.5f*(al[r]+bl));
    float nb = __shfl_xor(v, 1);
    if ((tid&1)==0) t2p[r][tid>>1] = pk_f16(v, nb);
  }
  __syncthreads();
  // on_s^T f16 t-pairs for PV: onsT[(b*256 + j)*64 + t/2]
  #pragma unroll
  for(int rr=0;rr<16;rr++){
    uint32 ua = t2p[2*rr][tid>>1], ub = t2p[2*rr+1][tid>>1];
    uint32 ha = (tid&1) ? (ua>>16) : (ua & 0xffffu);
    uint32 hb = (tid&1) ? (ub>>16) : (ub & 0xffffu);
    onsT[((size_t)b*H2 + tid)*64 + (t0>>1) + rr] = ha | (hb<<16);
  }
  // eb = exp(2*(on_s @ W2^T + b2))
  float ac[32];
  #pragma unroll
  for(int r=0;r<32;r++) ac[r]=0.f;
  for(int k8=0;k8<32;k8++){
    int k2=4*k8;
    uint32 w0=wp2[(size_t)(k2+0)*H2+tid], w1=wp2[(size_t)(k2+1)*H2+tid];
    uint32 w2=wp2[(size_t)(k2+2)*H2+tid], w3=wp2[(size_t)(k2+3)*H2+tid];
    #pragma unroll
    for(int r=0;r<32;r++){
      uint4 u = *(const uint4*)&t2p[r][k2];
      ac[r]=dot2(u.x,w0,ac[r]); ac[r]=dot2(u.y,w1,ac[r]);
      ac[r]=dot2(u.z,w2,ac[r]); ac[r]=dot2(u.w,w3,ac[r]);
    }
  }
  float bb=b2[tid];
  #pragma unroll
  for(int r=0;r<32;r++) ebg[(row0+r)*H2+tid]=__expf(2.0f*(ac[r]+bb));
}

// ---------- eq = exp(2*(concat(h0,h1)@W1T+b1)) via f16 dot2, b128 LDS ----------
__global__ __launch_bounds__(256) void qp_all_k(
  const uint32* __restrict__ h16, const uint32* __restrict__ wp1, const float* __restrict__ b1,
  float* __restrict__ eqg)
{
  int m0 = blockIdx.x*16; int b = m0>>7; int t0 = m0&127;
  __shared__ __align__(16) uint32 tile[16][128];
  int tid=threadIdx.x;
  for (int i=tid;i<16*128;i+=256){
    int r=i>>7, c=i&127; int dd=c>>6, kk2=c&63;
    tile[r][c] = h16[(((size_t)(t0+r)*2 + dd)*B + b)*64 + kk2];
  }
  __syncthreads();
  float ac[16];
  #pragma unroll
  for(int r=0;r<16;r++) ac[r]=0.f;
  for(int k8=0;k8<32;k8++){
    int k2=4*k8;
    uint32 w0=wp1[(size_t)(k2+0)*H2+tid], w1=wp1[(size_t)(k2+1)*H2+tid];
    uint32 w2=wp1[(size_t)(k2+2)*H2+tid], w3=wp1[(size_t)(k2+3)*H2+tid];
    #pragma unroll
    for(int r=0;r<16;r++){
      uint4 u = *(const uint4*)&tile[r][k2];
      ac[r]=dot2(u.x,w0,ac[r]); ac[r]=dot2(u.y,w1,ac[r]);
      ac[r]=dot2(u.z,w2,ac[r]); ac[r]=dot2(u.w,w3,ac[r]);
    }
  }
  float bb=b1[tid];
  #pragma unroll
  for(int r=0;r<16;r++) eqg[(size_t)(m0+r)*H2+tid]=__expf(2.0f*(ac[r]+bb));
}

// ---------- scores: grid (b, t-half of 64); TQ=4; eb in 64 f32 regs; (512,2) ----------
// eqs padded 20-dword jq-blocks (bank-clean b128). 2 barriers per 4 queries.
__global__ __launch_bounds__(512,2) void score_k(
  const float* __restrict__ eqg, const float* __restrict__ ebg,
  const float* __restrict__ att_v, uint32* __restrict__ sc16)
{
  int b  = blockIdx.x >> 1;
  int t0 = (blockIdx.x & 1) * 64;
  int tid = threadIdx.x;
  int jq = tid & 15, ttb = tid >> 4;
  __shared__ __align__(16) float eqs[2][4*320];   // [buf][q*320 + jq*20 + ii]
  __shared__ __align__(16) float scl[2][4][T];
  __shared__ float wsum8[2][8];
  __shared__ __align__(16) float wvsp[320];       // padded -2*att_v
  float eb0[16], eb1[16], eb2[16], eb3[16];
  float vsum_mine = 0.f;
  {
    const float* ebb = ebg + (size_t)b*T*H2;
    #pragma unroll
    for (int ii=0;ii<16;ii++){
      int j = 16*jq + ii;
      eb0[ii] = ebb[(size_t)(ttb    )*H2 + j];
      eb1[ii] = ebb[(size_t)(ttb+32 )*H2 + j];
      eb2[ii] = ebb[(size_t)(ttb+64 )*H2 + j];
      eb3[ii] = ebb[(size_t)(ttb+96 )*H2 + j];
      vsum_mine += att_v[j];
    }
  }
  if (tid < H2) wvsp[(tid>>4)*20 + (tid&15)] = -2.0f*att_v[tid];
  if (tid < 256){
    int q = tid>>6, l = 4*(tid&63);
    float4 v = ((const float4*)(eqg + ((size_t)b*T + t0 + q)*H2))[tid&63];
    *(float4*)&eqs[0][q*320 + (l>>4)*20 + (l&15)] = v;
  }
  __syncthreads();
  int buf = 0;
  for (int tq=0; tq<64; tq+=4){
    int cur = (tq>>2)&1;
    if (tq+4 < 64 && tid < 256){
      int q = tid>>6, l = 4*(tid&63);
      float4 v = ((const float4*)(eqg + ((size_t)b*T + t0+tq+4 + q)*H2))[tid&63];
      *(float4*)&eqs[buf^1][q*320 + (l>>4)*20 + (l&15)] = v;
    }
    const float* eqb = eqs[buf];
    float a00=vsum_mine,a01=vsum_mine,a02=vsum_mine,a03=vsum_mine;
    float a10=vsum_mine,a11=vsum_mine,a12=vsum_mine,a13=vsum_mine;
    float a20=vsum_mine,a21=vsum_mine,a22=vsum_mine,a23=vsum_mine;
    float a30=vsum_mine,a31=vsum_mine,a32=vsum_mine,a33=vsum_mine;
    #pragma unroll
    for (int ii4=0; ii4<4; ii4++){
      float4 q0 = *(const float4*)&eqb[        jq*20 + 4*ii4];
      float4 q1 = *(const float4*)&eqb[320   + jq*20 + 4*ii4];
      float4 q2 = *(const float4*)&eqb[2*320 + jq*20 + 4*ii4];
      float4 q3 = *(const float4*)&eqb[3*320 + jq*20 + 4*ii4];
      float4 w4 = *(const float4*)&wvsp[jq*20 + 4*ii4];
      #pragma unroll
      for (int c=0;c<4;c++){
        int ii = 4*ii4 + c;
        float e0=eb0[ii], e1=eb1[ii], e2=eb2[ii], e3=eb3[ii];
        float q0c = (c==0)?q0.x:(c==1)?q0.y:(c==2)?q0.z:q0.w;
        float q1c = (c==0)?q1.x:(c==1)?q1.y:(c==2)?q1.z:q1.w;
        float q2c = (c==0)?q2.x:(c==1)?q2.y:(c==2)?q2.z:q2.w;
        float q3c = (c==0)?q3.x:(c==1)?q3.y:(c==2)?q3.z:q3.w;
        float w   = (c==0)?w4.x:(c==1)?w4.y:(c==2)?w4.z:w4.w;
        a00 = fmaf(w, fast_rcp(fmaf(e0,q0c,1.f)), a00);
        a01 = fmaf(w, fast_rcp(fmaf(e1,q0c,1.f)), a01);
        a02 = fmaf(w, fast_rcp(fmaf(e2,q0c,1.f)), a02);
        a03 = fmaf(w, fast_rcp(fmaf(e3,q0c,1.f)), a03);
        a10 = fmaf(w, fast_rcp(fmaf(e0,q1c,1.f)), a10);
        a11 = fmaf(w, fast_rcp(fmaf(e1,q1c,1.f)), a11);
        a12 = fmaf(w, fast_rcp(fmaf(e2,q1c,1.f)), a12);
        a13 = fmaf(w, fast_rcp(fmaf(e3,q1c,1.f)), a13);
        a20 = fmaf(w, fast_rcp(fmaf(e0,q2c,1.f)), a20);
        a21 = fmaf(w, fast_rcp(fmaf(e1,q2c,1.f)), a21);
        a22 = fmaf(w, fast_rcp(fmaf(e2,q2c,1.f)), a22);
        a23 = fmaf(w, fast_rcp(fmaf(e3,q2c,1.f)), a23);
        a30 = fmaf(w, fast_rcp(fmaf(e0,q3c,1.f)), a30);
        a31 = fmaf(w, fast_rcp(fmaf(e1,q3c,1.f)), a31);
        a32 = fmaf(w, fast_rcp(fmaf(e2,q3c,1.f)), a32);
        a33 = fmaf(w, fast_rcp(fmaf(e3,q3c,1.f)), a33);
      }
    }
    #pragma unroll
    for (int off=1; off<16; off<<=1){
      a00 += __shfl_xor(a00,off); a01 += __shfl_xor(a01,off);
      a02 += __shfl_xor(a02,off); a03 += __shfl_xor(a03,off);
      a10 += __shfl_xor(a10,off); a11 += __shfl_xor(a11,off);
      a12 += __shfl_xor(a12,off); a13 += __shfl_xor(a13,off);
      a20 += __shfl_xor(a20,off); a21 += __shfl_xor(a21,off);
      a22 += __shfl_xor(a22,off); a23 += __shfl_xor(a23,off);
      a30 += __shfl_xor(a30,off); a31 += __shfl_xor(a31,off);
      a32 += __shfl_xor(a32,off); a33 += __shfl_xor(a33,off);
    }
    if (jq==0){
      scl[cur][0][ttb]=__expf(a00); scl[cur][0][ttb+32]=__expf(a01);
      scl[cur][0][ttb+64]=__expf(a02); scl[cur][0][ttb+96]=__expf(a03);
      scl[cur][1][ttb]=__expf(a10); scl[cur][1][ttb+32]=__expf(a11);
      scl[cur][1][ttb+64]=__expf(a12); scl[cur][1][ttb+96]=__expf(a13);
      scl[cur][2][ttb]=__expf(a20); scl[cur][2][ttb+32]=__expf(a21);
      scl[cur][2][ttb+64]=__expf(a22); scl[cur][2][ttb+96]=__expf(a23);
      scl[cur][3][ttb]=__expf(a30); scl[cur][3][ttb+32]=__expf(a31);
      scl[cur][3][ttb+64]=__expf(a32); scl[cur][3][ttb+96]=__expf(a33);
    }
    __syncthreads();                          // A: scl[cur] ready
    {
      int row = tid>>7;                       // 0..3 (all 512 threads)
      float e = scl[cur][row][tid&127];
      #pragma unroll
      for (int off=1; off<64; off<<=1) e += __shfl_xor(e,off);
      if ((tid&63)==0) wsum8[cur][tid>>6]=e;  // [row*2 + half]
    }
    __syncthreads();                          // B: wsum ready
    if (tid < 256){
      int row = tid>>6, i = tid&63;
      float tot = wsum8[cur][row*2] + wsum8[cur][row*2+1];
      float inv = fast_rcp(tot*128.0f);
      sc16[((size_t)b*T + t0+tq+row)*64 + i] =
        pk_f16(scl[cur][row][2*i]*inv, scl[cur][row][2*i+1]*inv);
    }
    buf ^= 1;
  }
}

// ---------- fused PV + output projection: ctx never leaves LDS ----------
__global__ __launch_bounds__(256,2) void pvout_k(
  const uint32* __restrict__ sc16, const uint32* __restrict__ onsT,
  const uint32* __restrict__ h16, const uint32* __restrict__ wpout,
  const float* __restrict__ bout, float* __restrict__ out)
{
  int b  = blockIdx.x >> 3;
  int t0 = (blockIdx.x & 7) * 16;
  int m0 = blockIdx.x*16;
  int tid = threadIdx.x;
  __shared__ uint32 scs[16][64];
  __shared__ __align__(16) uint32 rb[16][256];
  uint4 vreg[16];
  {
    const uint4* vp = (const uint4*)(onsT + ((size_t)b*H2 + tid)*64);
    #pragma unroll
    for (int k=0;k<16;k++) vreg[k] = vp[k];
  }
  for (int i=tid;i<1024;i+=256) ((uint32*)scs)[i] = sc16[((size_t)b*T + t0)*64 + i];
  for (int i=tid;i<16*128;i+=256){
    int r=i>>7, c=i&127;
    int t = t0+r;
    rb[r][c] = (c<64) ? h16[(((size_t)(t+1)*2 + 0)*B + b)*64 + c]
                      : h16[(((size_t)(t+1)*2 + 1)*B + b)*64 + (c-64)];
  }
  __syncthreads();
  for (int qt=0; qt<16; qt++){
    float a0=0.f,a1=0.f,a2=0.f,a3=0.f;
    #pragma unroll
    for (int k=0;k<16;k++){
      a0 = dot2(scs[qt][4*k+0], vreg[k].x, a0);
      a1 = dot2(scs[qt][4*k+1], vreg[k].y, a1);
      a2 = dot2(scs[qt][4*k+2], vreg[k].z, a2);
      a3 = dot2(scs[qt][4*k+3], vreg[k].w, a3);
    }
    float mine = (a0+a1)+(a2+a3);
    float nb = __shfl_xor(mine, 1);
    if ((tid&1)==0) rb[qt][128 + (tid>>1)] = pk_f16(mine, nb);
  }
  __syncthreads();
  for (int o=tid;o<16*D;o+=256){
    int r=o/D, j=o-r*D;
    float acc=bout[j];
    for (int k4=0;k4<64;k4++){
      uint4 u = *(const uint4*)&rb[r][4*k4];
      acc = dot2(u.x, wpout[(size_t)(4*k4+0)*D+j], acc);
      acc = dot2(u.y, wpout[(size_t)(4*k4+1)*D+j], acc);
      acc = dot2(u.z, wpout[(size_t)(4*k4+2)*D+j], acc);
      acc = dot2(u.w, wpout[(size_t)(4*k4+3)*D+j], acc);
    }
    out[((size_t)(m0+r))*D + j]=acc;
  }
}

extern "C" void kernel_launch(void* const* d_in, const int* in_sizes, int n_in,
                              void* d_out, int out_size, void* d_ws, size_t ws_size,
                              hipStream_t stream) {
  const float* x      =(const float*)d_in[0];
  const float* eps_z  =(const float*)d_in[1];
  const float* eps_on =(const float*)d_in[2];
  const float* enc_Wih=(const float*)d_in[3];
  const float* enc_Whh=(const float*)d_in[4];
  const float* enc_b  =(const float*)d_in[5];
  const float* dec_Wih=(const float*)d_in[6];
  const float* dec_Whh=(const float*)d_in[7];
  const float* dec_b  =(const float*)d_in[8];
  const float* Wzmu=(const float*)d_in[9];  const float* bzmu=(const float*)d_in[10];
  const float* Wzlv=(const float*)d_in[11]; const float* bzlv=(const float*)d_in[12];
  const float* Womu=(const float*)d_in[13]; const float* bomu=(const float*)d_in[14];
  const float* Wolv=(const float*)d_in[15]; const float* bolv=(const float*)d_in[16];
  const float* att_v=(const float*)d_in[17];
  const float* att_W1=(const float*)d_in[18]; const float* att_b1=(const float*)d_in[19];
  const float* att_W2=(const float*)d_in[20]; const float* att_b2=(const float*)d_in[21];
  const float* Wout=(const float*)d_in[22];  const float* bout=(const float*)d_in[23];
  float* out=(float*)d_out;
  float* ws=(float*)d_ws;
  (void)ws_size; (void)n_in; (void)in_sizes; (void)out_size;

  size_t o=0;
  float* WzmuT=ws+o; o+=H*H;
  float* WzlvT=ws+o; o+=H*H;
  uint32* wpkE=(uint32*)(ws+o); o+=65536;
  uint32* wpkD=(uint32*)(ws+o); o+=65536;
  uint32* wpmu=(uint32*)(ws+o); o+=32768;
  uint32* wplv=(uint32*)(ws+o); o+=32768;
  uint32* wp1 =(uint32*)(ws+o); o+=32768;
  uint32* wp2 =(uint32*)(ws+o); o+=32768;
  uint32* wpout=(uint32*)(ws+o); o+=19456;
  uint32* wxE =(uint32*)(ws+o); o+=38912;
  uint32* wxD =(uint32*)(ws+o); o+=38912;
  float* h_fin=ws+o; o+=2*B*H;
  __half* on16=(__half*)(ws+o); o+=(size_t)B*T*H2/2;
  uint32* h16 =(uint32*)(ws+o); o+=(size_t)(T+1)*2*B*64;
  float* Abase=ws+o; o+=16777216;                // 64MB: xgh (full) -> eqg (lower half)
  float* Cbase=ws+o; o+=14680064;                // 56MB: onsT 16MB + ebg 32MB + sc16 8MB

  __half* xgh = (__half*)Abase;
  float* eqg  = Abase;
  uint32* onsT = (uint32*)Cbase;
  float* ebg  = Cbase + 4194304;
  uint32* sc16 = (uint32*)(Cbase + 4194304 + 8388608);

  PrepArgs pa;
  {
    const float* srcs[2]={Wzmu,Wzlv};
    float* dsts[2]={WzmuT,WzlvT};
    for(int i=0;i<2;i++){pa.src[i]=srcs[i];pa.dst[i]=dsts[i];pa.R[i]=H;pa.C[i]=H;}
  }
  Pack2Args p2;
  {
    const float* srcs[9]={Womu,Wolv,att_W1,att_W2,Wout,
                          enc_Wih, enc_Wih + (size_t)512*76,
                          dec_Wih, dec_Wih + (size_t)512*76};
    uint32* dsts[9]={wpmu,wplv,wp1,wp2,wpout, wxE, wxE+19456, wxD, wxD+19456};
    int Ns[9]={H2,H2,H2,H2,D, 512,512,512,512};
    int Ks[9]={H2,H2,H2,H2,G, D,D,D,D};
    for(int i=0;i<9;i++){p2.src[i]=srcs[i];p2.dst[i]=dsts[i];p2.N[i]=Ns[i];p2.K[i]=Ks[i];}
  }
  prep_k<<<64,256,0,stream>>>(pa);
  pack2_k<<<288,256,0,stream>>>(p2);
  pack_whh_k<<<512,256,0,stream>>>(enc_Whh, dec_Whh, wpkE, wpkD);

  // encoder phase
  xg_k<<<4096,256,0,stream>>>(x, wxE, enc_b, xgh, 0);
  rec_k<1><<<512,512,0,stream>>>(xgh, wpkE, nullptr, on16, h_fin, nullptr);
  z_k<<<512,128,0,stream>>>(h_fin, WzmuT,bzmu,WzlvT,bzlv,eps_z, h16);
  onsw2v_k<<<1024,256,0,stream>>>((const uint32*)on16,wpmu,bomu,wplv,bolv,eps_on,wp2,att_b2,onsT,ebg);

  // decoder phase
  xg_k<<<4096,256,0,stream>>>(x, wxD, dec_b, xgh, 1);
  rec_k<0><<<512,512,0,stream>>>(xgh, wpkD, (const __half*)h16, nullptr, nullptr, h16);

  qp_all_k<<<2048,256,0,stream>>>(h16, wp1, att_b1, eqg);
  score_k<<<512,512,0,stream>>>(eqg, ebg, att_v, sc16);
  pvout_k<<<2048,256,0,stream>>>(sc16, onsT, h16, wpout, bout, out);
}

// Round 18
// 698.473 us; speedup vs baseline: 1.1464x; 1.1464x over previous
//
#include <hip/hip_runtime.h>
#include <hip/hip_fp16.h>

#define B 256
#define T 128
#define D 76
#define H 128
#define G 512   // 4H
#define H2 256  // 2H

typedef unsigned int uint32;
typedef unsigned short ushort16;
typedef _Float16 h2_t __attribute__((ext_vector_type(2)));
typedef _Float16 f16x8 __attribute__((ext_vector_type(8)));
typedef float f32x4 __attribute__((ext_vector_type(4)));

__device__ __forceinline__ float sigm(float x){ return 1.0f/(1.0f+__expf(-x)); }
__device__ __forceinline__ float fast_rcp(float x){ float r; asm volatile("v_rcp_f32 %0, %1" : "=v"(r) : "v"(x)); return r; }
__device__ __forceinline__ float fast_tanh(float x){ return 1.0f - 2.0f*fast_rcp(1.0f + __expf(2.0f*x)); }
__device__ __forceinline__ ushort16 f2bf(float f){ uint32 u=__float_as_uint(f); return (ushort16)((u + 0x7fffu + ((u>>16)&1u))>>16); }
__device__ __forceinline__ uint32 pk_f16(float a, float b){
  return (uint32)__half_as_ushort(__float2half(a)) | ((uint32)__half_as_ushort(__float2half(b))<<16);
}
__device__ __forceinline__ float dot2(uint32 w, uint32 h, float acc){
  return __builtin_amdgcn_fdot2(__builtin_bit_cast(h2_t, w), __builtin_bit_cast(h2_t, h), acc, false);
}
__device__ __forceinline__ f32x4 mfma16(uint4 a, uint4 b, f32x4 c){
  return __builtin_amdgcn_mfma_f32_16x16x32_f16(
    __builtin_bit_cast(f16x8, a), __builtin_bit_cast(f16x8, b), c, 0, 0, 0);
}

// ---------- weight transposes (2 segs: Wzmu, Wzlv) ----------
struct PrepArgs {
  const float* src[2];
  float* dst[2];
  int R[2]; int C[2];
};
__global__ __launch_bounds__(256) void prep_k(PrepArgs a){
  int seg = blockIdx.x >> 5;
  const float* s=a.src[seg]; float* d=a.dst[seg];
  int R=a.R[seg], C=a.C[seg], tot=R*C;
  for (int i=(blockIdx.x&31)*256+threadIdx.x; i<tot; i+=32*256){
    int r=i/C, c=i-r*C;
    d[(size_t)c*R + r] = s[i];
  }
}

// ---------- pack [N][K] f32 row-major -> [K/2][N] f16-pair u32 (9 segs) ----------
struct Pack2Args { const float* src[9]; uint32* dst[9]; int N[9]; int K[9]; };
__global__ __launch_bounds__(256) void pack2_k(Pack2Args a){
  int seg = blockIdx.x >> 5;
  const float* s=a.src[seg]; uint32* d=a.dst[seg];
  int N=a.N[seg], K=a.K[seg], tot=N*(K>>1);
  for (int i=(blockIdx.x&31)*256+threadIdx.x; i<tot; i+=32*256){
    int k2=i/N, j=i-k2*N;
    float2 w = *(const float2*)(s + (size_t)j*K + 2*k2);
    d[(size_t)k2*N + j] = pk_f16(w.x, w.y);
  }
}

// ---------- pack Whh (enc+dec) f16 k-pairs, columns PERMUTED for in-wave gate exchange ----------
__global__ __launch_bounds__(256) void pack_whh_k(
  const float* __restrict__ eWhh, const float* __restrict__ dWhh,
  uint32* __restrict__ wpkE, uint32* __restrict__ wpkD)
{
  int idx = blockIdx.x*256 + threadIdx.x;      // 131072 total
  int phase = idx >> 16;
  int rem = idx & 65535;
  int d = rem >> 15;
  int k2 = (rem >> 9) & 63;
  int jc = rem & 511;
  int gate = (jc>>4)&3;
  int cell = (jc&15) + 16*(jc>>6);
  int jsrc = gate*128 + cell;
  const float* Wsrc = phase ? dWhh : eWhh;
  float2 wa = *(const float2*)(Wsrc + ((size_t)(d*512 + jsrc))*128 + 2*k2);
  (phase ? wpkD : wpkE)[rem] = pk_f16(wa.x, wa.y);
}

// ---------- xg = x @ Wih^T + b via f16 dot2, flat f16 [d][b][t][512]. shift=1 for decoder ----------
__global__ __launch_bounds__(256) void xg_k(
  const float* __restrict__ x, const uint32* __restrict__ wx, const float* __restrict__ bias,
  __half* __restrict__ xgh, int shift)
{
  int d = blockIdx.x >> 11;
  int blk = blockIdx.x & 2047;
  int b = blk >> 3, t0 = (blk & 7) * 16;
  int tid = threadIdx.x;
  __shared__ __align__(16) uint32 xs[16][40];
  for (int i=tid;i<16*38;i+=256){
    int r=i/38, k2=i-r*38, ts=t0+r-shift;
    float2 xv = (ts>=0) ? *(const float2*)(x + ((size_t)b*T+ts)*D + 2*k2) : make_float2(0.f,0.f);
    xs[r][k2] = pk_f16(xv.x, xv.y);
  }
  __syncthreads();
  const uint32* W = wx + (size_t)d*38*512;
  float a0[16], a1[16];
  #pragma unroll
  for(int r=0;r<16;r++){a0[r]=0.f;a1[r]=0.f;}
  #pragma unroll
  for (int k8=0;k8<9;k8++){
    int k2=4*k8;
    uint32 w00=W[(size_t)(k2+0)*512+tid], w01=W[(size_t)(k2+0)*512+tid+256];
    uint32 w10=W[(size_t)(k2+1)*512+tid], w11=W[(size_t)(k2+1)*512+tid+256];
    uint32 w20=W[(size_t)(k2+2)*512+tid], w21=W[(size_t)(k2+2)*512+tid+256];
    uint32 w30=W[(size_t)(k2+3)*512+tid], w31=W[(size_t)(k2+3)*512+tid+256];
    #pragma unroll
    for(int r=0;r<16;r++){
      uint4 u = *(const uint4*)&xs[r][k2];
      a0[r]=dot2(u.x,w00,a0[r]); a0[r]=dot2(u.y,w10,a0[r]);
      a0[r]=dot2(u.z,w20,a0[r]); a0[r]=dot2(u.w,w30,a0[r]);
      a1[r]=dot2(u.x,w01,a1[r]); a1[r]=dot2(u.y,w11,a1[r]);
      a1[r]=dot2(u.z,w21,a1[r]); a1[r]=dot2(u.w,w31,a1[r]);
    }
  }
  {
    uint32 w00=W[(size_t)36*512+tid], w01=W[(size_t)36*512+tid+256];
    uint32 w10=W[(size_t)37*512+tid], w11=W[(size_t)37*512+tid+256];
    #pragma unroll
    for(int r=0;r<16;r++){
      uint2 u = *(const uint2*)&xs[r][36];
      a0[r]=dot2(u.x,w00,a0[r]); a0[r]=dot2(u.y,w10,a0[r]);
      a1[r]=dot2(u.x,w01,a1[r]); a1[r]=dot2(u.y,w11,a1[r]);
    }
  }
  float bb0=bias[d*G+tid], bb1=bias[d*G+tid+256];
  #pragma unroll
  for(int r=0;r<16;r++){
    size_t row = (size_t)(d*B + b)*T + (t0+r);
    xgh[row*512 + tid]       = __float2half(a0[r]+bb0);
    xgh[row*512 + tid + 256] = __float2half(a1[r]+bb1);
  }
}

// ---------- recurrence: in-wave gate exchange; 1 barrier/iter; hsd double-buffered ----------
template<int ENC>
__global__ __launch_bounds__(512,2) void rec_k(
  const __half* __restrict__ xgh, const uint32* __restrict__ wpk,
  const __half* __restrict__ h16r, __half* __restrict__ on16,
  float* __restrict__ h_fin, uint32* __restrict__ h16w)
{
  int d = blockIdx.x >> 8;
  int b = blockIdx.x & 255;
  int tid = threadIdx.x;
  int lane = tid & 63;
  int gate = lane >> 4;
  int cell = (lane & 15) + 16*(tid >> 6);
  int jmap = gate*128 + cell;
  __shared__ __align__(16) __half hsd[2][H];
  uint32 wreg[64];
  const uint32* wp = wpk + (size_t)d*64*512;
  #pragma unroll
  for (int k2=0;k2<64;k2++) wreg[k2] = wp[k2*512 + tid];
  if (tid < H){
    if (ENC) hsd[0][tid] = __float2half(0.f);
    else     hsd[0][tid] = h16r[((size_t)d*B + b)*H + tid];
  }
  float creg = 0.f, hlast = 0.f;
  const __half* xrow = xgh + (size_t)(d*B + b)*T*512;
  int te0 = ENC ? (d ? (T-1) : 0) : 0;
  __half xr_next = xrow[(size_t)te0*512 + jmap];
  __syncthreads();
  int p = 0;
  for (int t=0;t<T;t++){
    int te = ENC ? (d ? (T-1-t) : t) : t;
    __half xr = xr_next;
    if (t+1 < T){
      int tn = ENC ? (d ? (T-2-t) : (t+1)) : (t+1);
      xr_next = xrow[(size_t)tn*512 + jmap];
    }
    const uint4* h128 = (const uint4*)hsd[p];
    float acc0 = 0.f, acc1 = 0.f;
    #pragma unroll
    for (int k8=0;k8<16;k8++){
      uint4 hv4 = h128[k8];
      acc0 = dot2(wreg[4*k8+0], hv4.x, acc0);
      acc1 = dot2(wreg[4*k8+1], hv4.y, acc1);
      acc0 = dot2(wreg[4*k8+2], hv4.z, acc0);
      acc1 = dot2(wreg[4*k8+3], hv4.w, acc1);
    }
    float gpre = acc0 + acc1 + __half2float(xr);
    float kmul = (gate==2) ? 2.f : 1.f;
    float s = sigm(kmul*gpre);
    float act = (gate==2) ? fmaf(2.f, s, -1.f) : s;
    int src = lane & 15;
    float f_ = __shfl(act, src+16, 64);
    float g_ = __shfl(act, src+32, 64);
    float o_ = __shfl(act, src+48, 64);
    if (gate==0){
      creg = f_*creg + act*g_;
      float hv = o_*fast_tanh(creg);
      hlast = hv;
      hsd[p^1][cell] = __float2half(hv);
      if (ENC){
        on16[((size_t)b*T + te)*H2 + d*H + cell] = __float2half(hv);
      } else {
        float nb = __shfl_xor(hv, 1);
        if ((cell&1)==0)
          h16w[(((size_t)(t+1)*2 + d)*B + b)*64 + (cell>>1)] = pk_f16(hv, nb);
      }
    }
    __syncthreads();
    p ^= 1;
  }
  if (ENC && gate==0) h_fin[(size_t)d*B*H + (size_t)b*H + cell] = hlast;
}

// ---------- z = mu + eps*exp(0.5 lv) -> h16[0] (f16 pairs) ----------
__global__ __launch_bounds__(128) void z_k(
  const float* __restrict__ h_fin, const float* __restrict__ WzmuT, const float* __restrict__ bzmu,
  const float* __restrict__ WzlvT, const float* __restrict__ bzlv, const float* __restrict__ eps_z,
  uint32* __restrict__ h16w)
{
  __shared__ float hr[H];
  int d = blockIdx.x >> 8; int b = blockIdx.x & 255;
  int j = threadIdx.x;
  hr[j] = h_fin[(size_t)d*B*H + (size_t)b*H + j];
  __syncthreads();
  float mu=bzmu[j], lv=bzlv[j];
  #pragma unroll 4
  for(int k=0;k<H;k++){ float hv=hr[k]; mu+=hv*WzmuT[k*H+j]; lv+=hv*WzlvT[k*H+j]; }
  float z = mu + eps_z[(size_t)d*B*H + (size_t)b*H + j]*__expf(0.5f*lv);
  float nb = __shfl_xor(z, 1);
  if ((j&1)==0)
    h16w[(((size_t)0*2 + d)*B + b)*64 + (j>>1)] = pk_f16(z, nb);
}

// ---------- fused on_s via MFMA 16x16x32: onsT + eb ----------
// block 256 = 4 waves; M=32 rows, N=256 (wave owns 64-col quarter), K=256.
__global__ __launch_bounds__(256) void onsw2v_k(
  const uint32* __restrict__ on32, const uint32* __restrict__ wpmu, const float* __restrict__ bomu,
  const uint32* __restrict__ wplv, const float* __restrict__ bolv, const float* __restrict__ eps_on,
  const uint32* __restrict__ wp2, const float* __restrict__ b2,
  uint32* __restrict__ onsT, float* __restrict__ ebg)
{
  __shared__ __align__(16) uint32 tl[32][128];     // on (f16 pairs along k)
  __shared__ __align__(16) uint32 t2p[32][128];    // on_s (f16 pairs along col)
  size_t row0=(size_t)blockIdx.x*32;
  int b = (int)(row0 >> 7), t0 = (int)(row0 & 127);
  int tid=threadIdx.x;
  int wv = tid>>6, lane = tid&63;
  int n0 = wv*64;
  int lr = lane & 15, kq = lane >> 4;
  for(int i=tid;i<32*128;i+=256) ((uint32*)tl)[i] = on32[row0*128 + i];
  __syncthreads();
  f32x4 accM[2][4], accL[2][4];
  #pragma unroll
  for (int mt=0;mt<2;mt++)
    #pragma unroll
    for (int nt=0;nt<4;nt++){ accM[mt][nt]=(f32x4){0,0,0,0}; accL[mt][nt]=(f32x4){0,0,0,0}; }
  for (int kb=0;kb<8;kb++){
    int k2b = kb*16 + kq*4;
    uint4 aA0 = *(const uint4*)&tl[lr][k2b];
    uint4 aA1 = *(const uint4*)&tl[16+lr][k2b];
    #pragma unroll
    for (int nt=0;nt<4;nt++){
      int n = n0 + nt*16 + lr;
      uint4 bM, bL;
      bM.x = wpmu[(size_t)(k2b+0)*H2 + n]; bM.y = wpmu[(size_t)(k2b+1)*H2 + n];
      bM.z = wpmu[(size_t)(k2b+2)*H2 + n]; bM.w = wpmu[(size_t)(k2b+3)*H2 + n];
      bL.x = wplv[(size_t)(k2b+0)*H2 + n]; bL.y = wplv[(size_t)(k2b+1)*H2 + n];
      bL.z = wplv[(size_t)(k2b+2)*H2 + n]; bL.w = wplv[(size_t)(k2b+3)*H2 + n];
      accM[0][nt] = mfma16(aA0, bM, accM[0][nt]);
      accM[1][nt] = mfma16(aA1, bM, accM[1][nt]);
      accL[0][nt] = mfma16(aA0, bL, accL[0][nt]);
      accL[1][nt] = mfma16(aA1, bL, accL[1][nt]);
    }
  }
  // epilogue 1: VAE sample -> t2p (f16 pairs along col)
  #pragma unroll
  for (int mt=0;mt<2;mt++){
    #pragma unroll
    for (int nt=0;nt<4;nt++){
      int col = n0 + nt*16 + lr;
      float bm = bomu[col], bl = bolv[col];
      #pragma unroll
      for (int r=0;r<4;r++){
        int rl = mt*16 + kq*4 + r;
        size_t rowg = row0 + rl;
        float mu = accM[mt][nt][r] + bm;
        float lv = accL[mt][nt][r] + bl;
        float v = mu + eps_on[rowg*H2 + col]*__expf(0.5f*lv);
        float nb = __shfl_xor(v, 1);
        if ((lr&1)==0) t2p[rl][col>>1] = pk_f16(v, nb);
      }
    }
  }
  __syncthreads();
  // on_s^T f16 t-pairs for PV: onsT[(b*256 + j)*64 + t/2]
  #pragma unroll
  for(int rr=0;rr<16;rr++){
    uint32 ua = t2p[2*rr][tid>>1], ub = t2p[2*rr+1][tid>>1];
    uint32 ha = (tid&1) ? (ua>>16) : (ua & 0xffffu);
    uint32 hb = (tid&1) ? (ub>>16) : (ub & 0xffffu);
    onsT[((size_t)b*H2 + tid)*64 + (t0>>1) + rr] = ha | (hb<<16);
  }
  // GEMM3: eb = exp(2*(on_s @ W2^T + b2))
  f32x4 acc3[2][4];
  #pragma unroll
  for (int mt=0;mt<2;mt++)
    #pragma unroll
    for (int nt=0;nt<4;nt++) acc3[mt][nt]=(f32x4){0,0,0,0};
  for (int kb=0;kb<8;kb++){
    int k2b = kb*16 + kq*4;
    uint4 aA0 = *(const uint4*)&t2p[lr][k2b];
    uint4 aA1 = *(const uint4*)&t2p[16+lr][k2b];
    #pragma unroll
    for (int nt=0;nt<4;nt++){
      int n = n0 + nt*16 + lr;
      uint4 bW;
      bW.x = wp2[(size_t)(k2b+0)*H2 + n]; bW.y = wp2[(size_t)(k2b+1)*H2 + n];
      bW.z = wp2[(size_t)(k2b+2)*H2 + n]; bW.w = wp2[(size_t)(k2b+3)*H2 + n];
      acc3[0][nt] = mfma16(aA0, bW, acc3[0][nt]);
      acc3[1][nt] = mfma16(aA1, bW, acc3[1][nt]);
    }
  }
  #pragma unroll
  for (int mt=0;mt<2;mt++){
    #pragma unroll
    for (int nt=0;nt<4;nt++){
      int col = n0 + nt*16 + lr;
      float bb = b2[col];
      #pragma unroll
      for (int r=0;r<4;r++){
        int rl = mt*16 + kq*4 + r;
        ebg[(row0 + rl)*H2 + col] = __expf(2.0f*(acc3[mt][nt][r] + bb));
      }
    }
  }
}

// ---------- eq via MFMA 16x16x32: block 256 = 4 waves; M=32, N=256, K=256 ----------
__global__ __launch_bounds__(256) void qp_all_k(
  const uint32* __restrict__ h16, const uint32* __restrict__ wp1, const float* __restrict__ b1,
  float* __restrict__ eqg)
{
  int m0 = blockIdx.x*32; int b = m0>>7; int t0 = m0&127;
  __shared__ __align__(16) uint32 tile[32][128];
  int tid=threadIdx.x;
  int wv = tid>>6, lane = tid&63;
  int n0 = wv*64;
  int lr = lane & 15, kq = lane >> 4;
  for (int i=tid;i<32*128;i+=256){
    int r=i>>7, c=i&127; int dd=c>>6, kk2=c&63;
    tile[r][c] = h16[(((size_t)(t0+r)*2 + dd)*B + b)*64 + kk2];
  }
  __syncthreads();
  f32x4 acc[2][4];
  #pragma unroll
  for (int mt=0;mt<2;mt++)
    #pragma unroll
    for (int nt=0;nt<4;nt++) acc[mt][nt]=(f32x4){0,0,0,0};
  for (int kb=0;kb<8;kb++){
    int k2b = kb*16 + kq*4;
    uint4 aA0 = *(const uint4*)&tile[lr][k2b];
    uint4 aA1 = *(const uint4*)&tile[16+lr][k2b];
    #pragma unroll
    for (int nt=0;nt<4;nt++){
      int n = n0 + nt*16 + lr;
      uint4 bW;
      bW.x = wp1[(size_t)(k2b+0)*H2 + n]; bW.y = wp1[(size_t)(k2b+1)*H2 + n];
      bW.z = wp1[(size_t)(k2b+2)*H2 + n]; bW.w = wp1[(size_t)(k2b+3)*H2 + n];
      acc[0][nt] = mfma16(aA0, bW, acc[0][nt]);
      acc[1][nt] = mfma16(aA1, bW, acc[1][nt]);
    }
  }
  #pragma unroll
  for (int mt=0;mt<2;mt++){
    #pragma unroll
    for (int nt=0;nt<4;nt++){
      int col = n0 + nt*16 + lr;
      float bb = b1[col];
      #pragma unroll
      for (int r=0;r<4;r++){
        int rl = mt*16 + kq*4 + r;
        eqg[(size_t)(m0 + rl)*H2 + col] = __expf(2.0f*(acc[mt][nt][r] + bb));
      }
    }
  }
}

// ---------- scores: grid (b, t-half of 64); TQ=4; eb in 64 f32 regs; (512,2) ----------
__global__ __launch_bounds__(512,2) void score_k(
  const float* __restrict__ eqg, const float* __restrict__ ebg,
  const float* __restrict__ att_v, uint32* __restrict__ sc16)
{
  int b  = blockIdx.x >> 1;
  int t0 = (blockIdx.x & 1) * 64;
  int tid = threadIdx.x;
  int jq = tid & 15, ttb = tid >> 4;
  __shared__ __align__(16) float eqs[2][4*320];
  __shared__ __align__(16) float scl[2][4][T];
  __shared__ float wsum8[2][8];
  __shared__ __align__(16) float wvsp[320];
  float eb0[16], eb1[16], eb2[16], eb3[16];
  float vsum_mine = 0.f;
  {
    const float* ebb = ebg + (size_t)b*T*H2;
    #pragma unroll
    for (int ii=0;ii<16;ii++){
      int j = 16*jq + ii;
      eb0[ii] = ebb[(size_t)(ttb    )*H2 + j];
      eb1[ii] = ebb[(size_t)(ttb+32 )*H2 + j];
      eb2[ii] = ebb[(size_t)(ttb+64 )*H2 + j];
      eb3[ii] = ebb[(size_t)(ttb+96 )*H2 + j];
      vsum_mine += att_v[j];
    }
  }
  if (tid < H2) wvsp[(tid>>4)*20 + (tid&15)] = -2.0f*att_v[tid];
  if (tid < 256){
    int q = tid>>6, l = 4*(tid&63);
    float4 v = ((const float4*)(eqg + ((size_t)b*T + t0 + q)*H2))[tid&63];
    *(float4*)&eqs[0][q*320 + (l>>4)*20 + (l&15)] = v;
  }
  __syncthreads();
  int buf = 0;
  for (int tq=0; tq<64; tq+=4){
    int cur = (tq>>2)&1;
    if (tq+4 < 64 && tid < 256){
      int q = tid>>6, l = 4*(tid&63);
      float4 v = ((const float4*)(eqg + ((size_t)b*T + t0+tq+4 + q)*H2))[tid&63];
      *(float4*)&eqs[buf^1][q*320 + (l>>4)*20 + (l&15)] = v;
    }
    const float* eqb = eqs[buf];
    float a00=vsum_mine,a01=vsum_mine,a02=vsum_mine,a03=vsum_mine;
    float a10=vsum_mine,a11=vsum_mine,a12=vsum_mine,a13=vsum_mine;
    float a20=vsum_mine,a21=vsum_mine,a22=vsum_mine,a23=vsum_mine;
    float a30=vsum_mine,a31=vsum_mine,a32=vsum_mine,a33=vsum_mine;
    #pragma unroll
    for (int ii4=0; ii4<4; ii4++){
      float4 q0 = *(const float4*)&eqb[        jq*20 + 4*ii4];
      float4 q1 = *(const float4*)&eqb[320   + jq*20 + 4*ii4];
      float4 q2 = *(const float4*)&eqb[2*320 + jq*20 + 4*ii4];
      float4 q3 = *(const float4*)&eqb[3*320 + jq*20 + 4*ii4];
      float4 w4 = *(const float4*)&wvsp[jq*20 + 4*ii4];
      #pragma unroll
      for (int c=0;c<4;c++){
        int ii = 4*ii4 + c;
        float e0=eb0[ii], e1=eb1[ii], e2=eb2[ii], e3=eb3[ii];
        float q0c = (c==0)?q0.x:(c==1)?q0.y:(c==2)?q0.z:q0.w;
        float q1c = (c==0)?q1.x:(c==1)?q1.y:(c==2)?q1.z:q1.w;
        float q2c = (c==0)?q2.x:(c==1)?q2.y:(c==2)?q2.z:q2.w;
        float q3c = (c==0)?q3.x:(c==1)?q3.y:(c==2)?q3.z:q3.w;
        float w   = (c==0)?w4.x:(c==1)?w4.y:(c==2)?w4.z:w4.w;
        a00 = fmaf(w, fast_rcp(fmaf(e0,q0c,1.f)), a00);
        a01 = fmaf(w, fast_rcp(fmaf(e1,q0c,1.f)), a01);
        a02 = fmaf(w, fast_rcp(fmaf(e2,q0c,1.f)), a02);
        a03 = fmaf(w, fast_rcp(fmaf(e3,q0c,1.f)), a03);
        a10 = fmaf(w, fast_rcp(fmaf(e0,q1c,1.f)), a10);
        a11 = fmaf(w, fast_rcp(fmaf(e1,q1c,1.f)), a11);
        a12 = fmaf(w, fast_rcp(fmaf(e2,q1c,1.f)), a12);
        a13 = fmaf(w, fast_rcp(fmaf(e3,q1c,1.f)), a13);
        a20 = fmaf(w, fast_rcp(fmaf(e0,q2c,1.f)), a20);
        a21 = fmaf(w, fast_rcp(fmaf(e1,q2c,1.f)), a21);
        a22 = fmaf(w, fast_rcp(fmaf(e2,q2c,1.f)), a22);
        a23 = fmaf(w, fast_rcp(fmaf(e3,q2c,1.f)), a23);
        a30 = fmaf(w, fast_rcp(fmaf(e0,q3c,1.f)), a30);
        a31 = fmaf(w, fast_rcp(fmaf(e1,q3c,1.f)), a31);
        a32 = fmaf(w, fast_rcp(fmaf(e2,q3c,1.f)), a32);
        a33 = fmaf(w, fast_rcp(fmaf(e3,q3c,1.f)), a33);
      }
    }
    #pragma unroll
    for (int off=1; off<16; off<<=1){
      a00 += __shfl_xor(a00,off); a01 += __shfl_xor(a01,off);
      a02 += __shfl_xor(a02,off); a03 += __shfl_xor(a03,off);
      a10 += __shfl_xor(a10,off); a11 += __shfl_xor(a11,off);
      a12 += __shfl_xor(a12,off); a13 += __shfl_xor(a13,off);
      a20 += __shfl_xor(a20,off); a21 += __shfl_xor(a21,off);
      a22 += __shfl_xor(a22,off); a23 += __shfl_xor(a23,off);
      a30 += __shfl_xor(a30,off); a31 += __shfl_xor(a31,off);
      a32 += __shfl_xor(a32,off); a33 += __shfl_xor(a33,off);
    }
    if (jq==0){
      scl[cur][0][ttb]=__expf(a00); scl[cur][0][ttb+32]=__expf(a01);
      scl[cur][0][ttb+64]=__expf(a02); scl[cur][0][ttb+96]=__expf(a03);
      scl[cur][1][ttb]=__expf(a10); scl[cur][1][ttb+32]=__expf(a11);
      scl[cur][1][ttb+64]=__expf(a12); scl[cur][1][ttb+96]=__expf(a13);
      scl[cur][2][ttb]=__expf(a20); scl[cur][2][ttb+32]=__expf(a21);
      scl[cur][2][ttb+64]=__expf(a22); scl[cur][2][ttb+96]=__expf(a23);
      scl[cur][3][ttb]=__expf(a30); scl[cur][3][ttb+32]=__expf(a31);
      scl[cur][3][ttb+64]=__expf(a32); scl[cur][3][ttb+96]=__expf(a33);
    }
    __syncthreads();
    {
      int row = tid>>7;
      float e = scl[cur][row][tid&127];
      #pragma unroll
      for (int off=1; off<64; off<<=1) e += __shfl_xor(e,off);
      if ((tid&63)==0) wsum8[cur][tid>>6]=e;
    }
    __syncthreads();
    if (tid < 256){
      int row = tid>>6, i = tid&63;
      float tot = wsum8[cur][row*2] + wsum8[cur][row*2+1];
      float inv = fast_rcp(tot*128.0f);
      sc16[((size_t)b*T + t0+tq+row)*64 + i] =
        pk_f16(scl[cur][row][2*i]*inv, scl[cur][row][2*i+1]*inv);
    }
    buf ^= 1;
  }
}

// ---------- fused PV + output projection: ctx never leaves LDS ----------
__global__ __launch_bounds__(256,2) void pvout_k(
  const uint32* __restrict__ sc16, const uint32* __restrict__ onsT,
  const uint32* __restrict__ h16, const uint32* __restrict__ wpout,
  const float* __restrict__ bout, float* __restrict__ out)
{
  int b  = blockIdx.x >> 3;
  int t0 = (blockIdx.x & 7) * 16;
  int m0 = blockIdx.x*16;
  int tid = threadIdx.x;
  __shared__ uint32 scs[16][64];
  __shared__ __align__(16) uint32 rb[16][256];
  uint4 vreg[16];
  {
    const uint4* vp = (const uint4*)(onsT + ((size_t)b*H2 + tid)*64);
    #pragma unroll
    for (int k=0;k<16;k++) vreg[k] = vp[k];
  }
  for (int i=tid;i<1024;i+=256) ((uint32*)scs)[i] = sc16[((size_t)b*T + t0)*64 + i];
  for (int i=tid;i<16*128;i+=256){
    int r=i>>7, c=i&127;
    int t = t0+r;
    rb[r][c] = (c<64) ? h16[(((size_t)(t+1)*2 + 0)*B + b)*64 + c]
                      : h16[(((size_t)(t+1)*2 + 1)*B + b)*64 + (c-64)];
  }
  __syncthreads();
  for (int qt=0; qt<16; qt++){
    float a0=0.f,a1=0.f,a2=0.f,a3=0.f;
    #pragma unroll
    for (int k=0;k<16;k++){
      a0 = dot2(scs[qt][4*k+0], vreg[k].x, a0);
      a1 = dot2(scs[qt][4*k+1], vreg[k].y, a1);
      a2 = dot2(scs[qt][4*k+2], vreg[k].z, a2);
      a3 = dot2(scs[qt][4*k+3], vreg[k].w, a3);
    }
    float mine = (a0+a1)+(a2+a3);
    float nb = __shfl_xor(mine, 1);
    if ((tid&1)==0) rb[qt][128 + (tid>>1)] = pk_f16(mine, nb);
  }
  __syncthreads();
  for (int o=tid;o<16*D;o+=256){
    int r=o/D, j=o-r*D;
    float acc=bout[j];
    for (int k4=0;k4<64;k4++){
      uint4 u = *(const uint4*)&rb[r][4*k4];
      acc = dot2(u.x, wpout[(size_t)(4*k4+0)*D+j], acc);
      acc = dot2(u.y, wpout[(size_t)(4*k4+1)*D+j], acc);
      acc = dot2(u.z, wpout[(size_t)(4*k4+2)*D+j], acc);
      acc = dot2(u.w, wpout[(size_t)(4*k4+3)*D+j], acc);
    }
    out[((size_t)(m0+r))*D + j]=acc;
  }
}

extern "C" void kernel_launch(void* const* d_in, const int* in_sizes, int n_in,
                              void* d_out, int out_size, void* d_ws, size_t ws_size,
                              hipStream_t stream) {
  const float* x      =(const float*)d_in[0];
  const float* eps_z  =(const float*)d_in[1];
  const float* eps_on =(const float*)d_in[2];
  const float* enc_Wih=(const float*)d_in[3];
  const float* enc_Whh=(const float*)d_in[4];
  const float* enc_b  =(const float*)d_in[5];
  const float* dec_Wih=(const float*)d_in[6];
  const float* dec_Whh=(const float*)d_in[7];
  const float* dec_b  =(const float*)d_in[8];
  const float* Wzmu=(const float*)d_in[9];  const float* bzmu=(const float*)d_in[10];
  const float* Wzlv=(const float*)d_in[11]; const float* bzlv=(const float*)d_in[12];
  const float* Womu=(const float*)d_in[13]; const float* bomu=(const float*)d_in[14];
  const float* Wolv=(const float*)d_in[15]; const float* bolv=(const float*)d_in[16];
  const float* att_v=(const float*)d_in[17];
  const float* att_W1=(const float*)d_in[18]; const float* att_b1=(const float*)d_in[19];
  const float* att_W2=(const float*)d_in[20]; const float* att_b2=(const float*)d_in[21];
  const float* Wout=(const float*)d_in[22];  const float* bout=(const float*)d_in[23];
  float* out=(float*)d_out;
  float* ws=(float*)d_ws;
  (void)ws_size; (void)n_in; (void)in_sizes; (void)out_size;

  size_t o=0;
  float* WzmuT=ws+o; o+=H*H;
  float* WzlvT=ws+o; o+=H*H;
  uint32* wpkE=(uint32*)(ws+o); o+=65536;
  uint32* wpkD=(uint32*)(ws+o); o+=65536;
  uint32* wpmu=(uint32*)(ws+o); o+=32768;
  uint32* wplv=(uint32*)(ws+o); o+=32768;
  uint32* wp1 =(uint32*)(ws+o); o+=32768;
  uint32* wp2 =(uint32*)(ws+o); o+=32768;
  uint32* wpout=(uint32*)(ws+o); o+=19456;
  uint32* wxE =(uint32*)(ws+o); o+=38912;
  uint32* wxD =(uint32*)(ws+o); o+=38912;
  float* h_fin=ws+o; o+=2*B*H;
  __half* on16=(__half*)(ws+o); o+=(size_t)B*T*H2/2;
  uint32* h16 =(uint32*)(ws+o); o+=(size_t)(T+1)*2*B*64;
  float* Abase=ws+o; o+=16777216;                // 64MB: xgh (full) -> eqg (lower half)
  float* Cbase=ws+o; o+=14680064;                // 56MB: onsT 16MB + ebg 32MB + sc16 8MB

  __half* xgh = (__half*)Abase;
  float* eqg  = Abase;
  uint32* onsT = (uint32*)Cbase;
  float* ebg  = Cbase + 4194304;
  uint32* sc16 = (uint32*)(Cbase + 4194304 + 8388608);

  PrepArgs pa;
  {
    const float* srcs[2]={Wzmu,Wzlv};
    float* dsts[2]={WzmuT,WzlvT};
    for(int i=0;i<2;i++){pa.src[i]=srcs[i];pa.dst[i]=dsts[i];pa.R[i]=H;pa.C[i]=H;}
  }
  Pack2Args p2;
  {
    const float* srcs[9]={Womu,Wolv,att_W1,att_W2,Wout,
                          enc_Wih, enc_Wih + (size_t)512*76,
                          dec_Wih, dec_Wih + (size_t)512*76};
    uint32* dsts[9]={wpmu,wplv,wp1,wp2,wpout, wxE, wxE+19456, wxD, wxD+19456};
    int Ns[9]={H2,H2,H2,H2,D, 512,512,512,512};
    int Ks[9]={H2,H2,H2,H2,G, D,D,D,D};
    for(int i=0;i<9;i++){p2.src[i]=srcs[i];p2.dst[i]=dsts[i];p2.N[i]=Ns[i];p2.K[i]=Ks[i];}
  }
  prep_k<<<64,256,0,stream>>>(pa);
  pack2_k<<<288,256,0,stream>>>(p2);
  pack_whh_k<<<512,256,0,stream>>>(enc_Whh, dec_Whh, wpkE, wpkD);

  // encoder phase
  xg_k<<<4096,256,0,stream>>>(x, wxE, enc_b, xgh, 0);
  rec_k<1><<<512,512,0,stream>>>(xgh, wpkE, nullptr, on16, h_fin, nullptr);
  z_k<<<512,128,0,stream>>>(h_fin, WzmuT,bzmu,WzlvT,bzlv,eps_z, h16);
  onsw2v_k<<<1024,256,0,stream>>>((const uint32*)on16,wpmu,bomu,wplv,bolv,eps_on,wp2,att_b2,onsT,ebg);

  // decoder phase
  xg_k<<<4096,256,0,stream>>>(x, wxD, dec_b, xgh, 1);
  rec_k<0><<<512,512,0,stream>>>(xgh, wpkD, (const __half*)h16, nullptr, nullptr, h16);

  qp_all_k<<<1024,256,0,stream>>>(h16, wp1, att_b1, eqg);
  score_k<<<512,512,0,stream>>>(eqg, ebg, att_v, sc16);
  pvout_k<<<2048,256,0,stream>>>(sc16, onsT, h16, wpout, bout, out);
}

// Round 19
// 612.292 us; speedup vs baseline: 1.3078x; 1.1408x over previous
//
#include <hip/hip_runtime.h>
#include <hip/hip_fp16.h>

#define B 256
#define T 128
#define D 76
#define H 128
#define G 512   // 4H
#define H2 256  // 2H

typedef unsigned int uint32;
typedef unsigned short ushort16;
typedef _Float16 h2_t __attribute__((ext_vector_type(2)));
typedef _Float16 f16x8 __attribute__((ext_vector_type(8)));
typedef float f32x4 __attribute__((ext_vector_type(4)));

__device__ __forceinline__ float sigm(float x){ return 1.0f/(1.0f+__expf(-x)); }
__device__ __forceinline__ float fast_rcp(float x){ float r; asm volatile("v_rcp_f32 %0, %1" : "=v"(r) : "v"(x)); return r; }
__device__ __forceinline__ float fast_tanh(float x){ return 1.0f - 2.0f*fast_rcp(1.0f + __expf(2.0f*x)); }
__device__ __forceinline__ uint32 pk_f16(float a, float b){
  return (uint32)__half_as_ushort(__float2half(a)) | ((uint32)__half_as_ushort(__float2half(b))<<16);
}
__device__ __forceinline__ float dot2(uint32 w, uint32 h, float acc){
  return __builtin_amdgcn_fdot2(__builtin_bit_cast(h2_t, w), __builtin_bit_cast(h2_t, h), acc, false);
}
__device__ __forceinline__ f32x4 mfma16(uint4 a, uint4 b, f32x4 c){
  return __builtin_amdgcn_mfma_f32_16x16x32_f16(
    __builtin_bit_cast(f16x8, a), __builtin_bit_cast(f16x8, b), c, 0, 0, 0);
}

// ---------- weight transposes (2 segs: Wzmu, Wzlv) ----------
struct PrepArgs {
  const float* src[2];
  float* dst[2];
  int R[2]; int C[2];
};
__global__ __launch_bounds__(256) void prep_k(PrepArgs a){
  int seg = blockIdx.x >> 5;
  const float* s=a.src[seg]; float* d=a.dst[seg];
  int R=a.R[seg], C=a.C[seg], tot=R*C;
  for (int i=(blockIdx.x&31)*256+threadIdx.x; i<tot; i+=32*256){
    int r=i/C, c=i-r*C;
    d[(size_t)c*R + r] = s[i];
  }
}

// ---------- pack [N][K] f32 -> [KP2][NP] f16-pair u32, zero-padded (9 segs) ----------
struct Pack2Args { const float* src[9]; uint32* dst[9]; int N[9]; int NP[9]; int K[9]; int KP2[9]; };
__global__ __launch_bounds__(256) void pack2_k(Pack2Args a){
  int seg = blockIdx.x >> 5;
  const float* s=a.src[seg]; uint32* d=a.dst[seg];
  int N=a.N[seg], NP=a.NP[seg], K=a.K[seg], KP2=a.KP2[seg];
  int tot=NP*KP2;
  for (int i=(blockIdx.x&31)*256+threadIdx.x; i<tot; i+=32*256){
    int k2=i/NP, j=i-k2*NP;
    uint32 v = 0;
    if (j < N && 2*k2 < K){
      float2 w = *(const float2*)(s + (size_t)j*K + 2*k2);
      v = pk_f16(w.x, w.y);
    }
    d[(size_t)k2*NP + j] = v;
  }
}

// ---------- pack Whh (enc+dec) f16 k-pairs, columns PERMUTED for in-wave gate exchange ----------
__global__ __launch_bounds__(256) void pack_whh_k(
  const float* __restrict__ eWhh, const float* __restrict__ dWhh,
  uint32* __restrict__ wpkE, uint32* __restrict__ wpkD)
{
  int idx = blockIdx.x*256 + threadIdx.x;      // 131072 total
  int phase = idx >> 16;
  int rem = idx & 65535;
  int d = rem >> 15;
  int k2 = (rem >> 9) & 63;
  int jc = rem & 511;
  int gate = (jc>>4)&3;
  int cell = (jc&15) + 16*(jc>>6);
  int jsrc = gate*128 + cell;
  const float* Wsrc = phase ? dWhh : eWhh;
  float2 wa = *(const float2*)(Wsrc + ((size_t)(d*512 + jsrc))*128 + 2*k2);
  (phase ? wpkD : wpkE)[rem] = pk_f16(wa.x, wa.y);
}

// ---------- xg via MFMA 16x16x32: M=32 rows, N=512, K=96 (padded). grid 2048 ----------
__global__ __launch_bounds__(256) void xg_k(
  const float* __restrict__ x, const uint32* __restrict__ wx, const float* __restrict__ bias,
  uint32* __restrict__ xgp, int shift)
{
  int m0 = blockIdx.x*32;
  int d = m0 >> 15;
  int rem = m0 & 32767;
  int b = rem >> 7, t0 = rem & 127;
  int tid = threadIdx.x;
  int wv = tid>>6, lane = tid&63;
  int n0 = wv*128;                       // wave owns 128 gates = 8 n-tiles
  int lr = lane & 15, kq = lane >> 4;
  __shared__ __align__(16) uint32 xs[32][48];
  for (int i=tid;i<32*48;i+=256){
    int r=i/48, k2=i-r*48, ts=t0+r-shift;
    float2 xv = (k2<38 && ts>=0) ? *(const float2*)(x + ((size_t)b*T+ts)*D + 2*k2)
                                 : make_float2(0.f,0.f);
    xs[r][k2] = pk_f16(xv.x, xv.y);
  }
  __syncthreads();
  const uint32* W = wx + (size_t)d*48*512;
  f32x4 acc[2][8];
  #pragma unroll
  for (int mt=0;mt<2;mt++)
    #pragma unroll
    for (int nt=0;nt<8;nt++) acc[mt][nt]=(f32x4){0,0,0,0};
  #pragma unroll
  for (int kb=0;kb<3;kb++){
    int k2b = kb*16 + kq*4;
    uint4 a0 = *(const uint4*)&xs[lr][k2b];
    uint4 a1 = *(const uint4*)&xs[16+lr][k2b];
    #pragma unroll
    for (int nt=0;nt<8;nt++){
      int n = n0 + nt*16 + lr;
      uint4 bw;
      bw.x = W[(size_t)(k2b+0)*512 + n]; bw.y = W[(size_t)(k2b+1)*512 + n];
      bw.z = W[(size_t)(k2b+2)*512 + n]; bw.w = W[(size_t)(k2b+3)*512 + n];
      acc[0][nt] = mfma16(a0, bw, acc[0][nt]);
      acc[1][nt] = mfma16(a1, bw, acc[1][nt]);
    }
  }
  #pragma unroll
  for (int mt=0;mt<2;mt++){
    #pragma unroll
    for (int nt=0;nt<8;nt++){
      int col = n0 + nt*16 + lr;
      float bb = bias[d*G + col];
      #pragma unroll
      for (int r=0;r<4;r++){
        int rl = mt*16 + kq*4 + r;
        float v = acc[mt][nt][r] + bb;
        float nb = __shfl_xor(v, 1);
        if ((lr&1)==0)
          xgp[((size_t)(m0+rl)*512 + col)>>1] = pk_f16(v, nb);
      }
    }
  }
}

// ---------- recurrence: in-wave gate exchange; 1 barrier/iter; hsd double-buffered ----------
template<int ENC>
__global__ __launch_bounds__(512,2) void rec_k(
  const __half* __restrict__ xgh, const uint32* __restrict__ wpk,
  const __half* __restrict__ h16r, __half* __restrict__ on16,
  float* __restrict__ h_fin, uint32* __restrict__ h16w)
{
  int d = blockIdx.x >> 8;
  int b = blockIdx.x & 255;
  int tid = threadIdx.x;
  int lane = tid & 63;
  int gate = lane >> 4;
  int cell = (lane & 15) + 16*(tid >> 6);
  int jmap = gate*128 + cell;
  __shared__ __align__(16) __half hsd[2][H];
  uint32 wreg[64];
  const uint32* wp = wpk + (size_t)d*64*512;
  #pragma unroll
  for (int k2=0;k2<64;k2++) wreg[k2] = wp[k2*512 + tid];
  if (tid < H){
    if (ENC) hsd[0][tid] = __float2half(0.f);
    else     hsd[0][tid] = h16r[((size_t)d*B + b)*H + tid];
  }
  float creg = 0.f, hlast = 0.f;
  const __half* xrow = xgh + (size_t)(d*B + b)*T*512;
  int te0 = ENC ? (d ? (T-1) : 0) : 0;
  __half xr_next = xrow[(size_t)te0*512 + jmap];
  __syncthreads();
  int p = 0;
  for (int t=0;t<T;t++){
    int te = ENC ? (d ? (T-1-t) : t) : t;
    __half xr = xr_next;
    if (t+1 < T){
      int tn = ENC ? (d ? (T-2-t) : (t+1)) : (t+1);
      xr_next = xrow[(size_t)tn*512 + jmap];
    }
    const uint4* h128 = (const uint4*)hsd[p];
    float acc0 = 0.f, acc1 = 0.f;
    #pragma unroll
    for (int k8=0;k8<16;k8++){
      uint4 hv4 = h128[k8];
      acc0 = dot2(wreg[4*k8+0], hv4.x, acc0);
      acc1 = dot2(wreg[4*k8+1], hv4.y, acc1);
      acc0 = dot2(wreg[4*k8+2], hv4.z, acc0);
      acc1 = dot2(wreg[4*k8+3], hv4.w, acc1);
    }
    float gpre = acc0 + acc1 + __half2float(xr);
    float kmul = (gate==2) ? 2.f : 1.f;
    float s = sigm(kmul*gpre);
    float act = (gate==2) ? fmaf(2.f, s, -1.f) : s;
    int src = lane & 15;
    float f_ = __shfl(act, src+16, 64);
    float g_ = __shfl(act, src+32, 64);
    float o_ = __shfl(act, src+48, 64);
    if (gate==0){
      creg = f_*creg + act*g_;
      float hv = o_*fast_tanh(creg);
      hlast = hv;
      hsd[p^1][cell] = __float2half(hv);
      if (ENC){
        on16[((size_t)b*T + te)*H2 + d*H + cell] = __float2half(hv);
      } else {
        float nb = __shfl_xor(hv, 1);
        if ((cell&1)==0)
          h16w[(((size_t)(t+1)*2 + d)*B + b)*64 + (cell>>1)] = pk_f16(hv, nb);
      }
    }
    __syncthreads();
    p ^= 1;
  }
  if (ENC && gate==0) h_fin[(size_t)d*B*H + (size_t)b*H + cell] = hlast;
}

// ---------- z = mu + eps*exp(0.5 lv) -> h16[0] (f16 pairs) ----------
__global__ __launch_bounds__(128) void z_k(
  const float* __restrict__ h_fin, const float* __restrict__ WzmuT, const float* __restrict__ bzmu,
  const float* __restrict__ WzlvT, const float* __restrict__ bzlv, const float* __restrict__ eps_z,
  uint32* __restrict__ h16w)
{
  __shared__ float hr[H];
  int d = blockIdx.x >> 8; int b = blockIdx.x & 255;
  int j = threadIdx.x;
  hr[j] = h_fin[(size_t)d*B*H + (size_t)b*H + j];
  __syncthreads();
  float mu=bzmu[j], lv=bzlv[j];
  #pragma unroll 4
  for(int k=0;k<H;k++){ float hv=hr[k]; mu+=hv*WzmuT[k*H+j]; lv+=hv*WzlvT[k*H+j]; }
  float z = mu + eps_z[(size_t)d*B*H + (size_t)b*H + j]*__expf(0.5f*lv);
  float nb = __shfl_xor(z, 1);
  if ((j&1)==0)
    h16w[(((size_t)0*2 + d)*B + b)*64 + (j>>1)] = pk_f16(z, nb);
}

// ---------- fused on_s via MFMA 16x16x32: onsT + eb ----------
__global__ __launch_bounds__(256) void onsw2v_k(
  const uint32* __restrict__ on32, const uint32* __restrict__ wpmu, const float* __restrict__ bomu,
  const uint32* __restrict__ wplv, const float* __restrict__ bolv, const float* __restrict__ eps_on,
  const uint32* __restrict__ wp2, const float* __restrict__ b2,
  uint32* __restrict__ onsT, float* __restrict__ ebg)
{
  __shared__ __align__(16) uint32 tl[32][128];
  __shared__ __align__(16) uint32 t2p[32][128];
  size_t row0=(size_t)blockIdx.x*32;
  int b = (int)(row0 >> 7), t0 = (int)(row0 & 127);
  int tid=threadIdx.x;
  int wv = tid>>6, lane = tid&63;
  int n0 = wv*64;
  int lr = lane & 15, kq = lane >> 4;
  for(int i=tid;i<32*128;i+=256) ((uint32*)tl)[i] = on32[row0*128 + i];
  __syncthreads();
  f32x4 accM[2][4], accL[2][4];
  #pragma unroll
  for (int mt=0;mt<2;mt++)
    #pragma unroll
    for (int nt=0;nt<4;nt++){ accM[mt][nt]=(f32x4){0,0,0,0}; accL[mt][nt]=(f32x4){0,0,0,0}; }
  for (int kb=0;kb<8;kb++){
    int k2b = kb*16 + kq*4;
    uint4 aA0 = *(const uint4*)&tl[lr][k2b];
    uint4 aA1 = *(const uint4*)&tl[16+lr][k2b];
    #pragma unroll
    for (int nt=0;nt<4;nt++){
      int n = n0 + nt*16 + lr;
      uint4 bM, bL;
      bM.x = wpmu[(size_t)(k2b+0)*H2 + n]; bM.y = wpmu[(size_t)(k2b+1)*H2 + n];
      bM.z = wpmu[(size_t)(k2b+2)*H2 + n]; bM.w = wpmu[(size_t)(k2b+3)*H2 + n];
      bL.x = wplv[(size_t)(k2b+0)*H2 + n]; bL.y = wplv[(size_t)(k2b+1)*H2 + n];
      bL.z = wplv[(size_t)(k2b+2)*H2 + n]; bL.w = wplv[(size_t)(k2b+3)*H2 + n];
      accM[0][nt] = mfma16(aA0, bM, accM[0][nt]);
      accM[1][nt] = mfma16(aA1, bM, accM[1][nt]);
      accL[0][nt] = mfma16(aA0, bL, accL[0][nt]);
      accL[1][nt] = mfma16(aA1, bL, accL[1][nt]);
    }
  }
  #pragma unroll
  for (int mt=0;mt<2;mt++){
    #pragma unroll
    for (int nt=0;nt<4;nt++){
      int col = n0 + nt*16 + lr;
      float bm = bomu[col], bl = bolv[col];
      #pragma unroll
      for (int r=0;r<4;r++){
        int rl = mt*16 + kq*4 + r;
        size_t rowg = row0 + rl;
        float mu = accM[mt][nt][r] + bm;
        float lv = accL[mt][nt][r] + bl;
        float v = mu + eps_on[rowg*H2 + col]*__expf(0.5f*lv);
        float nb = __shfl_xor(v, 1);
        if ((lr&1)==0) t2p[rl][col>>1] = pk_f16(v, nb);
      }
    }
  }
  __syncthreads();
  #pragma unroll
  for(int rr=0;rr<16;rr++){
    uint32 ua = t2p[2*rr][tid>>1], ub = t2p[2*rr+1][tid>>1];
    uint32 ha = (tid&1) ? (ua>>16) : (ua & 0xffffu);
    uint32 hb = (tid&1) ? (ub>>16) : (ub & 0xffffu);
    onsT[((size_t)b*H2 + tid)*64 + (t0>>1) + rr] = ha | (hb<<16);
  }
  f32x4 acc3[2][4];
  #pragma unroll
  for (int mt=0;mt<2;mt++)
    #pragma unroll
    for (int nt=0;nt<4;nt++) acc3[mt][nt]=(f32x4){0,0,0,0};
  for (int kb=0;kb<8;kb++){
    int k2b = kb*16 + kq*4;
    uint4 aA0 = *(const uint4*)&t2p[lr][k2b];
    uint4 aA1 = *(const uint4*)&t2p[16+lr][k2b];
    #pragma unroll
    for (int nt=0;nt<4;nt++){
      int n = n0 + nt*16 + lr;
      uint4 bW;
      bW.x = wp2[(size_t)(k2b+0)*H2 + n]; bW.y = wp2[(size_t)(k2b+1)*H2 + n];
      bW.z = wp2[(size_t)(k2b+2)*H2 + n]; bW.w = wp2[(size_t)(k2b+3)*H2 + n];
      acc3[0][nt] = mfma16(aA0, bW, acc3[0][nt]);
      acc3[1][nt] = mfma16(aA1, bW, acc3[1][nt]);
    }
  }
  #pragma unroll
  for (int mt=0;mt<2;mt++){
    #pragma unroll
    for (int nt=0;nt<4;nt++){
      int col = n0 + nt*16 + lr;
      float bb = b2[col];
      #pragma unroll
      for (int r=0;r<4;r++){
        int rl = mt*16 + kq*4 + r;
        ebg[(row0 + rl)*H2 + col] = __expf(2.0f*(acc3[mt][nt][r] + bb));
      }
    }
  }
}

// ---------- eq via MFMA 16x16x32: block 256 = 4 waves; M=32, N=256, K=256 ----------
__global__ __launch_bounds__(256) void qp_all_k(
  const uint32* __restrict__ h16, const uint32* __restrict__ wp1, const float* __restrict__ b1,
  float* __restrict__ eqg)
{
  int m0 = blockIdx.x*32; int b = m0>>7; int t0 = m0&127;
  __shared__ __align__(16) uint32 tile[32][128];
  int tid=threadIdx.x;
  int wv = tid>>6, lane = tid&63;
  int n0 = wv*64;
  int lr = lane & 15, kq = lane >> 4;
  for (int i=tid;i<32*128;i+=256){
    int r=i>>7, c=i&127; int dd=c>>6, kk2=c&63;
    tile[r][c] = h16[(((size_t)(t0+r)*2 + dd)*B + b)*64 + kk2];
  }
  __syncthreads();
  f32x4 acc[2][4];
  #pragma unroll
  for (int mt=0;mt<2;mt++)
    #pragma unroll
    for (int nt=0;nt<4;nt++) acc[mt][nt]=(f32x4){0,0,0,0};
  for (int kb=0;kb<8;kb++){
    int k2b = kb*16 + kq*4;
    uint4 aA0 = *(const uint4*)&tile[lr][k2b];
    uint4 aA1 = *(const uint4*)&tile[16+lr][k2b];
    #pragma unroll
    for (int nt=0;nt<4;nt++){
      int n = n0 + nt*16 + lr;
      uint4 bW;
      bW.x = wp1[(size_t)(k2b+0)*H2 + n]; bW.y = wp1[(size_t)(k2b+1)*H2 + n];
      bW.z = wp1[(size_t)(k2b+2)*H2 + n]; bW.w = wp1[(size_t)(k2b+3)*H2 + n];
      acc[0][nt] = mfma16(aA0, bW, acc[0][nt]);
      acc[1][nt] = mfma16(aA1, bW, acc[1][nt]);
    }
  }
  #pragma unroll
  for (int mt=0;mt<2;mt++){
    #pragma unroll
    for (int nt=0;nt<4;nt++){
      int col = n0 + nt*16 + lr;
      float bb = b1[col];
      #pragma unroll
      for (int r=0;r<4;r++){
        int rl = mt*16 + kq*4 + r;
        eqg[(size_t)(m0 + rl)*H2 + col] = __expf(2.0f*(acc[mt][nt][r] + bb));
      }
    }
  }
}

// ---------- scores: grid (b, t-half of 64); TQ=4; eb in 64 f32 regs; (512,2) ----------
__global__ __launch_bounds__(512,2) void score_k(
  const float* __restrict__ eqg, const float* __restrict__ ebg,
  const float* __restrict__ att_v, uint32* __restrict__ sc16)
{
  int b  = blockIdx.x >> 1;
  int t0 = (blockIdx.x & 1) * 64;
  int tid = threadIdx.x;
  int jq = tid & 15, ttb = tid >> 4;
  __shared__ __align__(16) float eqs[2][4*320];
  __shared__ __align__(16) float scl[2][4][T];
  __shared__ float wsum8[2][8];
  __shared__ __align__(16) float wvsp[320];
  float eb0[16], eb1[16], eb2[16], eb3[16];
  float vsum_mine = 0.f;
  {
    const float* ebb = ebg + (size_t)b*T*H2;
    #pragma unroll
    for (int ii=0;ii<16;ii++){
      int j = 16*jq + ii;
      eb0[ii] = ebb[(size_t)(ttb    )*H2 + j];
      eb1[ii] = ebb[(size_t)(ttb+32 )*H2 + j];
      eb2[ii] = ebb[(size_t)(ttb+64 )*H2 + j];
      eb3[ii] = ebb[(size_t)(ttb+96 )*H2 + j];
      vsum_mine += att_v[j];
    }
  }
  if (tid < H2) wvsp[(tid>>4)*20 + (tid&15)] = -2.0f*att_v[tid];
  if (tid < 256){
    int q = tid>>6, l = 4*(tid&63);
    float4 v = ((const float4*)(eqg + ((size_t)b*T + t0 + q)*H2))[tid&63];
    *(float4*)&eqs[0][q*320 + (l>>4)*20 + (l&15)] = v;
  }
  __syncthreads();
  int buf = 0;
  for (int tq=0; tq<64; tq+=4){
    int cur = (tq>>2)&1;
    if (tq+4 < 64 && tid < 256){
      int q = tid>>6, l = 4*(tid&63);
      float4 v = ((const float4*)(eqg + ((size_t)b*T + t0+tq+4 + q)*H2))[tid&63];
      *(float4*)&eqs[buf^1][q*320 + (l>>4)*20 + (l&15)] = v;
    }
    const float* eqb = eqs[buf];
    float a00=vsum_mine,a01=vsum_mine,a02=vsum_mine,a03=vsum_mine;
    float a10=vsum_mine,a11=vsum_mine,a12=vsum_mine,a13=vsum_mine;
    float a20=vsum_mine,a21=vsum_mine,a22=vsum_mine,a23=vsum_mine;
    float a30=vsum_mine,a31=vsum_mine,a32=vsum_mine,a33=vsum_mine;
    #pragma unroll
    for (int ii4=0; ii4<4; ii4++){
      float4 q0 = *(const float4*)&eqb[        jq*20 + 4*ii4];
      float4 q1 = *(const float4*)&eqb[320   + jq*20 + 4*ii4];
      float4 q2 = *(const float4*)&eqb[2*320 + jq*20 + 4*ii4];
      float4 q3 = *(const float4*)&eqb[3*320 + jq*20 + 4*ii4];
      float4 w4 = *(const float4*)&wvsp[jq*20 + 4*ii4];
      #pragma unroll
      for (int c=0;c<4;c++){
        int ii = 4*ii4 + c;
        float e0=eb0[ii], e1=eb1[ii], e2=eb2[ii], e3=eb3[ii];
        float q0c = (c==0)?q0.x:(c==1)?q0.y:(c==2)?q0.z:q0.w;
        float q1c = (c==0)?q1.x:(c==1)?q1.y:(c==2)?q1.z:q1.w;
        float q2c = (c==0)?q2.x:(c==1)?q2.y:(c==2)?q2.z:q2.w;
        float q3c = (c==0)?q3.x:(c==1)?q3.y:(c==2)?q3.z:q3.w;
        float w   = (c==0)?w4.x:(c==1)?w4.y:(c==2)?w4.z:w4.w;
        a00 = fmaf(w, fast_rcp(fmaf(e0,q0c,1.f)), a00);
        a01 = fmaf(w, fast_rcp(fmaf(e1,q0c,1.f)), a01);
        a02 = fmaf(w, fast_rcp(fmaf(e2,q0c,1.f)), a02);
        a03 = fmaf(w, fast_rcp(fmaf(e3,q0c,1.f)), a03);
        a10 = fmaf(w, fast_rcp(fmaf(e0,q1c,1.f)), a10);
        a11 = fmaf(w, fast_rcp(fmaf(e1,q1c,1.f)), a11);
        a12 = fmaf(w, fast_rcp(fmaf(e2,q1c,1.f)), a12);
        a13 = fmaf(w, fast_rcp(fmaf(e3,q1c,1.f)), a13);
        a20 = fmaf(w, fast_rcp(fmaf(e0,q2c,1.f)), a20);
        a21 = fmaf(w, fast_rcp(fmaf(e1,q2c,1.f)), a21);
        a22 = fmaf(w, fast_rcp(fmaf(e2,q2c,1.f)), a22);
        a23 = fmaf(w, fast_rcp(fmaf(e3,q2c,1.f)), a23);
        a30 = fmaf(w, fast_rcp(fmaf(e0,q3c,1.f)), a30);
        a31 = fmaf(w, fast_rcp(fmaf(e1,q3c,1.f)), a31);
        a32 = fmaf(w, fast_rcp(fmaf(e2,q3c,1.f)), a32);
        a33 = fmaf(w, fast_rcp(fmaf(e3,q3c,1.f)), a33);
      }
    }
    #pragma unroll
    for (int off=1; off<16; off<<=1){
      a00 += __shfl_xor(a00,off); a01 += __shfl_xor(a01,off);
      a02 += __shfl_xor(a02,off); a03 += __shfl_xor(a03,off);
      a10 += __shfl_xor(a10,off); a11 += __shfl_xor(a11,off);
      a12 += __shfl_xor(a12,off); a13 += __shfl_xor(a13,off);
      a20 += __shfl_xor(a20,off); a21 += __shfl_xor(a21,off);
      a22 += __shfl_xor(a22,off); a23 += __shfl_xor(a23,off);
      a30 += __shfl_xor(a30,off); a31 += __shfl_xor(a31,off);
      a32 += __shfl_xor(a32,off); a33 += __shfl_xor(a33,off);
    }
    if (jq==0){
      scl[cur][0][ttb]=__expf(a00); scl[cur][0][ttb+32]=__expf(a01);
      scl[cur][0][ttb+64]=__expf(a02); scl[cur][0][ttb+96]=__expf(a03);
      scl[cur][1][ttb]=__expf(a10); scl[cur][1][ttb+32]=__expf(a11);
      scl[cur][1][ttb+64]=__expf(a12); scl[cur][1][ttb+96]=__expf(a13);
      scl[cur][2][ttb]=__expf(a20); scl[cur][2][ttb+32]=__expf(a21);
      scl[cur][2][ttb+64]=__expf(a22); scl[cur][2][ttb+96]=__expf(a23);
      scl[cur][3][ttb]=__expf(a30); scl[cur][3][ttb+32]=__expf(a31);
      scl[cur][3][ttb+64]=__expf(a32); scl[cur][3][ttb+96]=__expf(a33);
    }
    __syncthreads();
    {
      int row = tid>>7;
      float e = scl[cur][row][tid&127];
      #pragma unroll
      for (int off=1; off<64; off<<=1) e += __shfl_xor(e,off);
      if ((tid&63)==0) wsum8[cur][tid>>6]=e;
    }
    __syncthreads();
    if (tid < 256){
      int row = tid>>6, i = tid&63;
      float tot = wsum8[cur][row*2] + wsum8[cur][row*2+1];
      float inv = fast_rcp(tot*128.0f);
      sc16[((size_t)b*T + t0+tq+row)*64 + i] =
        pk_f16(scl[cur][row][2*i]*inv, scl[cur][row][2*i+1]*inv);
    }
    buf ^= 1;
  }
}

// ---------- fused PV + outproj, both via MFMA ----------
// PV: M=16 (queries), K=128 (4 kb), N=256 (4 waves x 4 n-tiles).
// outproj: M=16, K=512 (16 kb), N=80 padded (5 n-tiles round-robin over waves).
__global__ __launch_bounds__(256,2) void pvout_k(
  const uint32* __restrict__ sc16, const uint32* __restrict__ onsT,
  const uint32* __restrict__ h16, const uint32* __restrict__ wpout,
  const float* __restrict__ bout, float* __restrict__ out)
{
  int b  = blockIdx.x >> 3;
  int t0 = (blockIdx.x & 7) * 16;
  int m0 = blockIdx.x*16;
  int tid = threadIdx.x;
  int wv = tid>>6, lane = tid&63;
  int lr = lane & 15, kq = lane >> 4;
  __shared__ __align__(16) uint32 scs[16][64];
  __shared__ __align__(16) uint32 rb[16][256];
  for (int i=tid;i<1024;i+=256) ((uint32*)scs)[i] = sc16[((size_t)b*T + t0)*64 + i];
  for (int i=tid;i<16*128;i+=256){
    int r=i>>7, c=i&127;
    int t = t0+r;
    rb[r][c] = (c<64) ? h16[(((size_t)(t+1)*2 + 0)*B + b)*64 + c]
                      : h16[(((size_t)(t+1)*2 + 1)*B + b)*64 + (c-64)];
  }
  __syncthreads();
  // phase A: PV via MFMA -> ctx into rb[.][128..255]
  {
    int n0 = wv*64;
    f32x4 accP[4];
    #pragma unroll
    for (int nt=0;nt<4;nt++) accP[nt]=(f32x4){0,0,0,0};
    #pragma unroll
    for (int kb=0;kb<4;kb++){
      int k2b = kb*16 + kq*4;
      uint4 a = *(const uint4*)&scs[lr][k2b];
      #pragma unroll
      for (int nt=0;nt<4;nt++){
        int j = n0 + nt*16 + lr;
        uint4 bw = *(const uint4*)(onsT + ((size_t)b*H2 + j)*64 + k2b);
        accP[nt] = mfma16(a, bw, accP[nt]);
      }
    }
    #pragma unroll
    for (int nt=0;nt<4;nt++){
      int j = n0 + nt*16 + lr;
      #pragma unroll
      for (int r=0;r<4;r++){
        int row = kq*4 + r;
        float v = accP[nt][r];
        float nb = __shfl_xor(v, 1);
        if ((lr&1)==0) rb[row][128 + (j>>1)] = pk_f16(v, nb);
      }
    }
  }
  __syncthreads();
  // phase B: outproj via MFMA
  for (int tt=wv; tt<5; tt+=4){
    f32x4 acc = (f32x4){0,0,0,0};
    #pragma unroll
    for (int kb=0;kb<16;kb++){
      int k2b = kb*16 + kq*4;
      uint4 a = *(const uint4*)&rb[lr][k2b];
      uint4 bw;
      bw.x = wpout[(size_t)(k2b+0)*80 + tt*16+lr]; bw.y = wpout[(size_t)(k2b+1)*80 + tt*16+lr];
      bw.z = wpout[(size_t)(k2b+2)*80 + tt*16+lr]; bw.w = wpout[(size_t)(k2b+3)*80 + tt*16+lr];
      acc = mfma16(a, bw, acc);
    }
    int col = tt*16 + lr;
    if (col < D){
      float bb = bout[col];
      #pragma unroll
      for (int r=0;r<4;r++)
        out[(size_t)(m0 + kq*4 + r)*D + col] = acc[r] + bb;
    }
  }
}

extern "C" void kernel_launch(void* const* d_in, const int* in_sizes, int n_in,
                              void* d_out, int out_size, void* d_ws, size_t ws_size,
                              hipStream_t stream) {
  const float* x      =(const float*)d_in[0];
  const float* eps_z  =(const float*)d_in[1];
  const float* eps_on =(const float*)d_in[2];
  const float* enc_Wih=(const float*)d_in[3];
  const float* enc_Whh=(const float*)d_in[4];
  const float* enc_b  =(const float*)d_in[5];
  const float* dec_Wih=(const float*)d_in[6];
  const float* dec_Whh=(const float*)d_in[7];
  const float* dec_b  =(const float*)d_in[8];
  const float* Wzmu=(const float*)d_in[9];  const float* bzmu=(const float*)d_in[10];
  const float* Wzlv=(const float*)d_in[11]; const float* bzlv=(const float*)d_in[12];
  const float* Womu=(const float*)d_in[13]; const float* bomu=(const float*)d_in[14];
  const float* Wolv=(const float*)d_in[15]; const float* bolv=(const float*)d_in[16];
  const float* att_v=(const float*)d_in[17];
  const float* att_W1=(const float*)d_in[18]; const float* att_b1=(const float*)d_in[19];
  const float* att_W2=(const float*)d_in[20]; const float* att_b2=(const float*)d_in[21];
  const float* Wout=(const float*)d_in[22];  const float* bout=(const float*)d_in[23];
  float* out=(float*)d_out;
  float* ws=(float*)d_ws;
  (void)ws_size; (void)n_in; (void)in_sizes; (void)out_size;

  size_t o=0;
  float* WzmuT=ws+o; o+=H*H;
  float* WzlvT=ws+o; o+=H*H;
  uint32* wpkE=(uint32*)(ws+o); o+=65536;
  uint32* wpkD=(uint32*)(ws+o); o+=65536;
  uint32* wpmu=(uint32*)(ws+o); o+=32768;    // [128][256]
  uint32* wplv=(uint32*)(ws+o); o+=32768;
  uint32* wp1 =(uint32*)(ws+o); o+=32768;
  uint32* wp2 =(uint32*)(ws+o); o+=32768;
  uint32* wpout=(uint32*)(ws+o); o+=20480;   // [256][80] padded
  uint32* wxE =(uint32*)(ws+o); o+=49152;    // [d][48][512] padded
  uint32* wxD =(uint32*)(ws+o); o+=49152;
  float* h_fin=ws+o; o+=2*B*H;
  __half* on16=(__half*)(ws+o); o+=(size_t)B*T*H2/2;
  uint32* h16 =(uint32*)(ws+o); o+=(size_t)(T+1)*2*B*64;
  float* Abase=ws+o; o+=16777216;                // 64MB: xgh (full) -> eqg (lower half)
  float* Cbase=ws+o; o+=14680064;                // 56MB: onsT 16MB + ebg 32MB + sc16 8MB

  uint32* xgp = (uint32*)Abase;                  // f16 pairs view of xgh
  __half* xgh = (__half*)Abase;
  float* eqg  = Abase;
  uint32* onsT = (uint32*)Cbase;
  float* ebg  = Cbase + 4194304;
  uint32* sc16 = (uint32*)(Cbase + 4194304 + 8388608);

  PrepArgs pa;
  {
    const float* srcs[2]={Wzmu,Wzlv};
    float* dsts[2]={WzmuT,WzlvT};
    for(int i=0;i<2;i++){pa.src[i]=srcs[i];pa.dst[i]=dsts[i];pa.R[i]=H;pa.C[i]=H;}
  }
  Pack2Args p2;
  {
    const float* srcs[9]={Womu,Wolv,att_W1,att_W2,Wout,
                          enc_Wih, enc_Wih + (size_t)512*76,
                          dec_Wih, dec_Wih + (size_t)512*76};
    uint32* dsts[9]={wpmu,wplv,wp1,wp2,wpout, wxE, wxE+24576, wxD, wxD+24576};
    int Ns [9]={H2,H2,H2,H2, D, 512,512,512,512};
    int NPs[9]={H2,H2,H2,H2, 80, 512,512,512,512};
    int Ks [9]={H2,H2,H2,H2, G, D,D,D,D};
    int KP2[9]={128,128,128,128, 256, 48,48,48,48};
    for(int i=0;i<9;i++){p2.src[i]=srcs[i];p2.dst[i]=dsts[i];p2.N[i]=Ns[i];p2.NP[i]=NPs[i];p2.K[i]=Ks[i];p2.KP2[i]=KP2[i];}
  }
  prep_k<<<64,256,0,stream>>>(pa);
  pack2_k<<<288,256,0,stream>>>(p2);
  pack_whh_k<<<512,256,0,stream>>>(enc_Whh, dec_Whh, wpkE, wpkD);

  // encoder phase
  xg_k<<<2048,256,0,stream>>>(x, wxE, enc_b, xgp, 0);
  rec_k<1><<<512,512,0,stream>>>(xgh, wpkE, nullptr, on16, h_fin, nullptr);
  z_k<<<512,128,0,stream>>>(h_fin, WzmuT,bzmu,WzlvT,bzlv,eps_z, h16);
  onsw2v_k<<<1024,256,0,stream>>>((const uint32*)on16,wpmu,bomu,wplv,bolv,eps_on,wp2,att_b2,onsT,ebg);

  // decoder phase
  xg_k<<<2048,256,0,stream>>>(x, wxD, dec_b, xgp, 1);
  rec_k<0><<<512,512,0,stream>>>(xgh, wpkD, (const __half*)h16, nullptr, nullptr, h16);

  qp_all_k<<<1024,256,0,stream>>>(h16, wp1, att_b1, eqg);
  score_k<<<512,512,0,stream>>>(eqg, ebg, att_v, sc16);
  pvout_k<<<2048,256,0,stream>>>(sc16, onsT, h16, wpout, bout, out);
}